// Round 1
// baseline (708.758 us; speedup 1.0000x reference)
//
#include <hip/hip_runtime.h>

// ---------------------------------------------------------------------------
// CausalSelfAttention (GQA, 4 query sets sharing K/V)
//   B=8, T=1024, C=1024, H=16, hd=64, G=4
//   x:      [8,1024,1024] fp32
//   W_attn: [6144,1024]   fp32   (rows: Q0,Q1,Q2,Q3,K,V each 1024)
//   W_proj: [1024,4096]   fp32
//   out:    [8,1024,1024] fp32
// Pipeline: GEMM1(qkv, bf16 out) -> flash attn (Y bf16) -> GEMM2 (fp32 out)
// Workspace: qkv 8192*6144 bf16 (100.7MB) + Y 8192*4096 bf16 (67.1MB)
// ---------------------------------------------------------------------------

#define DEVI __device__ __forceinline__

typedef __attribute__((ext_vector_type(4))) float f32x4;
typedef __attribute__((ext_vector_type(8))) short bf16x8;
typedef __attribute__((ext_vector_type(4))) short bf16x4;

static DEVI short f2bf(float f) {
    union { float f; unsigned int i; } c; c.f = f;
    unsigned int i = c.i;
    unsigned int r = i + 0x7FFFu + ((i >> 16) & 1u);   // RNE
    return (short)(r >> 16);
}

// ---------------------------------------------------------------------------
// NT GEMM: C[M,N] = A[M,K] * B[N,K]^T.  B always fp32 (weights).
// A fp32 (A_F32=true) or bf16.  C fp32 (OUT_F32=true) or bf16.
// 128x128 tile, 4 waves (2x2) each 64x64, BK=32, mfma 16x16x32 bf16.
// ---------------------------------------------------------------------------
template<bool A_F32, bool OUT_F32>
__global__ __launch_bounds__(256)
void gemm_nt(const void* __restrict__ Ap, const float* __restrict__ Bp,
             void* __restrict__ Cp, int M, int N, int K) {
    const int LDT = 56;                 // padded LDS stride (bf16 elems); 112B, 16B-aligned
    __shared__ short As[128 * 56];
    __shared__ short Bs[128 * 56];

    const int tid  = threadIdx.x;
    const int lane = tid & 63;
    const int wid  = tid >> 6;
    const int wr   = wid >> 1;          // wave row (0..1)
    const int wc   = wid & 1;           // wave col (0..1)
    const int brow = blockIdx.y * 128;
    const int bcol = blockIdx.x * 128;

    const float* Af = (const float*)Ap;
    const short* Ab = (const short*)Ap;

    f32x4 acc[4][4] = {};

    const int l15 = lane & 15;
    const int g8  = (lane >> 4) * 8;

    for (int k0 = 0; k0 < K; k0 += 32) {
        // ---- stage A tile (128 x 32) ----
        if (A_F32) {
            #pragma unroll
            for (int i = 0; i < 4; i++) {
                int idx = tid + i * 256;          // 1024 float4 slots
                int r = idx >> 3, c4 = idx & 7;
                float4 v = *(const float4*)(Af + (size_t)(brow + r) * K + k0 + c4 * 4);
                bf16x4 t;
                t[0] = f2bf(v.x); t[1] = f2bf(v.y); t[2] = f2bf(v.z); t[3] = f2bf(v.w);
                *(bf16x4*)(&As[r * LDT + c4 * 4]) = t;
            }
        } else {
            #pragma unroll
            for (int i = 0; i < 2; i++) {
                int idx = tid + i * 256;          // 512 slots of 8 bf16
                int r = idx >> 2, c8 = idx & 3;
                uint4 v = *(const uint4*)(Ab + (size_t)(brow + r) * K + k0 + c8 * 8);
                *(uint4*)(&As[r * LDT + c8 * 8]) = v;
            }
        }
        // ---- stage B tile (128 x 32), fp32 -> bf16 ----
        #pragma unroll
        for (int i = 0; i < 4; i++) {
            int idx = tid + i * 256;
            int r = idx >> 3, c4 = idx & 7;
            float4 v = *(const float4*)(Bp + (size_t)(bcol + r) * K + k0 + c4 * 4);
            bf16x4 t;
            t[0] = f2bf(v.x); t[1] = f2bf(v.y); t[2] = f2bf(v.z); t[3] = f2bf(v.w);
            *(bf16x4*)(&Bs[r * LDT + c4 * 4]) = t;
        }
        __syncthreads();

        bf16x8 a[4], b[4];
        #pragma unroll
        for (int m = 0; m < 4; m++)
            a[m] = *(const bf16x8*)(&As[(wr * 64 + m * 16 + l15) * LDT + g8]);
        #pragma unroll
        for (int n = 0; n < 4; n++)
            b[n] = *(const bf16x8*)(&Bs[(wc * 64 + n * 16 + l15) * LDT + g8]);
        #pragma unroll
        for (int m = 0; m < 4; m++)
            #pragma unroll
            for (int n = 0; n < 4; n++)
                acc[m][n] = __builtin_amdgcn_mfma_f32_16x16x32_bf16(a[m], b[n], acc[m][n], 0, 0, 0);
        __syncthreads();
    }

    // ---- epilogue: C/D layout col=lane&15, row=(lane>>4)*4+j (verified m89) ----
    const int r0 = brow + wr * 64 + (lane >> 4) * 4;
    const int c0 = bcol + wc * 64 + l15;
    if (OUT_F32) {
        float* C = (float*)Cp;
        #pragma unroll
        for (int m = 0; m < 4; m++)
            #pragma unroll
            for (int n = 0; n < 4; n++)
                #pragma unroll
                for (int j = 0; j < 4; j++)
                    C[(size_t)(r0 + m * 16 + j) * N + c0 + n * 16] = acc[m][n][j];
    } else {
        short* C = (short*)Cp;
        #pragma unroll
        for (int m = 0; m < 4; m++)
            #pragma unroll
            for (int n = 0; n < 4; n++)
                #pragma unroll
                for (int j = 0; j < 4; j++)
                    C[(size_t)(r0 + m * 16 + j) * N + c0 + n * 16] = f2bf(acc[m][n][j]);
    }
}

// ---------------------------------------------------------------------------
// Flash attention over bf16 qkv.
//   qkv row i = b*1024+t, cols: [g*1024+h*64+d]=Q_g, [4096+h*64+d]=K, [5120+h*64+d]=V
//   block: (blockIdx.x = b*64 + h*4 + g, blockIdx.y = q-tile of 64 rows)
//   4 waves x 16 q-rows.  KV tiles of 64.  Online softmax, fp32 state.
//   Y[8192][4096] bf16, col = g*1024 + h*64 + d.
// ---------------------------------------------------------------------------
__global__ __launch_bounds__(256)
void attn_fwd(const short* __restrict__ qkv, short* __restrict__ Y) {
    const int LDK = 72;                     // padded stride (144B, 16B-aligned)
    __shared__ short Ks[64 * 72];           // K tile  [kv][hd]
    __shared__ short Vs[64 * 72];           // V tile transposed [d][kv]
    __shared__ short Ps[4][16 * 72];        // per-wave P tile [qrow][kv]

    const int tid  = threadIdx.x;
    const int lane = tid & 63;
    const int w    = tid >> 6;
    const int l15  = lane & 15;
    const int g8   = (lane >> 4) * 8;

    const int combo = blockIdx.x;
    const int g = combo & 3;
    const int h = (combo >> 2) & 15;
    const int b = combo >> 6;
    const int qt = blockIdx.y;

    const size_t RS = 6144;                 // qkv row stride (elems)

    // Q fragments: row = qt*64 + w*16 + l15, k = s*32 + g8 + j  (A-frag layout)
    bf16x8 qf[2];
    {
        size_t qrow = (size_t)(b * 1024 + qt * 64 + w * 16 + l15);
        const short* qp = qkv + qrow * RS + g * 1024 + h * 64 + g8;
        qf[0] = *(const bf16x8*)(qp);
        qf[1] = *(const bf16x8*)(qp + 32);
    }

    f32x4 o[4] = {};                        // output acc, d-frags (C layout)
    float mrow[4], lrow[4];
    #pragma unroll
    for (int j = 0; j < 4; j++) { mrow[j] = -1e30f; lrow[j] = 0.f; }

    for (int kvt = 0; kvt <= qt; kvt++) {
        __syncthreads();                    // protect prev tile reads
        // ---- stage K (linear) and V (transposed) ----
        #pragma unroll
        for (int i = 0; i < 2; i++) {
            int idx = tid + i * 256;        // 512 slots: 64 rows x 8 segs
            int r = idx >> 3, seg = idx & 7;
            size_t grow = (size_t)(b * 1024 + kvt * 64 + r);
            const short* kp = qkv + grow * RS + 4096 + h * 64 + seg * 8;
            *(uint4*)(&Ks[r * LDK + seg * 8]) = *(const uint4*)kp;
            const short* vp = qkv + grow * RS + 5120 + h * 64 + seg * 8;
            uint4 vv = *(const uint4*)vp;
            const short* ve = (const short*)&vv;
            #pragma unroll
            for (int j2 = 0; j2 < 8; j2++)
                Vs[(seg * 8 + j2) * LDK + r] = ve[j2];
        }
        __syncthreads();

        // ---- S = (Q K^T) * scale ----
        f32x4 s[4];
        #pragma unroll
        for (int c = 0; c < 4; c++) {
            f32x4 z = {};
            #pragma unroll
            for (int ks = 0; ks < 2; ks++) {
                bf16x8 kb = *(const bf16x8*)(&Ks[(c * 16 + l15) * LDK + ks * 32 + g8]);
                z = __builtin_amdgcn_mfma_f32_16x16x32_bf16(qf[ks], kb, z, 0, 0, 0);
            }
            s[c] = z * 0.125f;
        }

        // ---- causal mask (only on diagonal tile) ----
        if (kvt == qt) {
            int qlo = qt * 64 + w * 16 + (lane >> 4) * 4;
            #pragma unroll
            for (int c = 0; c < 4; c++) {
                int kvcol = kvt * 64 + c * 16 + l15;
                #pragma unroll
                for (int j = 0; j < 4; j++)
                    if (kvcol > qlo + j) s[c][j] = -1e30f;
            }
        }

        // ---- online softmax: row stats (reduce over cols = lanes l15) ----
        float pm[4];
        #pragma unroll
        for (int j = 0; j < 4; j++)
            pm[j] = fmaxf(fmaxf(s[0][j], s[1][j]), fmaxf(s[2][j], s[3][j]));
        #pragma unroll
        for (int off = 1; off < 16; off <<= 1)
            #pragma unroll
            for (int j = 0; j < 4; j++)
                pm[j] = fmaxf(pm[j], __shfl_xor(pm[j], off));

        float alpha[4], mnew[4];
        #pragma unroll
        for (int j = 0; j < 4; j++) {
            mnew[j] = fmaxf(mrow[j], pm[j]);
            alpha[j] = __expf(mrow[j] - mnew[j]);
            mrow[j] = mnew[j];
        }
        float psum[4] = {0.f, 0.f, 0.f, 0.f};
        #pragma unroll
        for (int c = 0; c < 4; c++)
            #pragma unroll
            for (int j = 0; j < 4; j++) {
                float e = __expf(s[c][j] - mnew[j]);
                s[c][j] = e;
                psum[j] += e;
            }
        #pragma unroll
        for (int off = 1; off < 16; off <<= 1)
            #pragma unroll
            for (int j = 0; j < 4; j++)
                psum[j] += __shfl_xor(psum[j], off);
        #pragma unroll
        for (int j = 0; j < 4; j++)
            lrow[j] = lrow[j] * alpha[j] + psum[j];
        #pragma unroll
        for (int c2 = 0; c2 < 4; c2++)
            #pragma unroll
            for (int j = 0; j < 4; j++)
                o[c2][j] *= alpha[j];

        // ---- P: C-layout -> A-layout via per-wave LDS (per-wave DS is in-order) ----
        short* pw = &Ps[w][0];
        #pragma unroll
        for (int c = 0; c < 4; c++)
            #pragma unroll
            for (int j = 0; j < 4; j++)
                pw[((lane >> 4) * 4 + j) * LDK + c * 16 + l15] = f2bf(s[c][j]);

        // ---- O += P V ----
        #pragma unroll
        for (int c2 = 0; c2 < 4; c2++) {
            #pragma unroll
            for (int s2 = 0; s2 < 2; s2++) {
                bf16x8 pa = *(const bf16x8*)(&pw[l15 * LDK + s2 * 32 + g8]);
                bf16x8 vb = *(const bf16x8*)(&Vs[(c2 * 16 + l15) * LDK + s2 * 32 + g8]);
                o[c2] = __builtin_amdgcn_mfma_f32_16x16x32_bf16(pa, vb, o[c2], 0, 0, 0);
            }
        }
    }

    // ---- epilogue: Y[row][g*1024 + h*64 + d] ----
    float inv[4];
    #pragma unroll
    for (int j = 0; j < 4; j++) inv[j] = 1.0f / lrow[j];
    const size_t yr0 = (size_t)(b * 1024 + qt * 64 + w * 16 + (lane >> 4) * 4);
    const int ycol0 = g * 1024 + h * 64 + l15;
    #pragma unroll
    for (int c2 = 0; c2 < 4; c2++)
        #pragma unroll
        for (int j = 0; j < 4; j++)
            Y[(yr0 + j) * 4096 + ycol0 + c2 * 16] = f2bf(o[c2][j] * inv[j]);
}

// ---------------------------------------------------------------------------
extern "C" void kernel_launch(void* const* d_in, const int* in_sizes, int n_in,
                              void* d_out, int out_size, void* d_ws, size_t ws_size,
                              hipStream_t stream) {
    const float* x  = (const float*)d_in[0];   // [8192,1024]
    const float* Wa = (const float*)d_in[1];   // [6144,1024]
    const float* Wp = (const float*)d_in[2];   // [1024,4096]
    float* out = (float*)d_out;                // [8192,1024]

    short* qkv = (short*)d_ws;                        // 8192*6144 bf16
    short* Yb  = qkv + (size_t)8192 * 6144;           // 8192*4096 bf16

    dim3 blk(256);
    // qkv = x @ W_attn^T   (M=8192, N=6144, K=1024)
    gemm_nt<true, false><<<dim3(6144 / 128, 8192 / 128), blk, 0, stream>>>(
        (const void*)x, Wa, (void*)qkv, 8192, 6144, 1024);
    // flash attention -> Y
    attn_fwd<<<dim3(512, 16), blk, 0, stream>>>(qkv, Yb);
    // out = Y @ W_proj^T   (M=8192, N=1024, K=4096)
    gemm_nt<false, true><<<dim3(1024 / 128, 8192 / 128), blk, 0, stream>>>(
        (const void*)Yb, Wp, (void*)out, 8192, 1024, 4096);
}

// Round 2
// 511.569 us; speedup vs baseline: 1.3855x; 1.3855x over previous
//
#include <hip/hip_runtime.h>

// ---------------------------------------------------------------------------
// CausalSelfAttention (GQA, 4 query sets sharing K/V)
//   B=8, T=1024, C=1024, H=16, hd=64, G=4
// Pipeline: cvt(x,Wa)->bf16, GEMM1 (gload_lds), flash attn (2 qsets/block,
// gathered V^T), cvt(Wp), GEMM2.
// ws layout (shorts):
//   qkv  [8192*6144] @ 0          (Wpb reuses first 4.2M after attn)
//   Yb   [8192*4096] @ 50331648   (xb, Wab live here before attn)
// ---------------------------------------------------------------------------

#define DEVI __device__ __forceinline__

typedef __attribute__((ext_vector_type(4))) float f32x4;
typedef __attribute__((ext_vector_type(8))) short bf16x8;

static DEVI short f2bf(float f) {
    union { float f; unsigned int i; } c; c.f = f;
    unsigned int i = c.i;
    unsigned int r = i + 0x7FFFu + ((i >> 16) & 1u);   // RNE
    return (short)(r >> 16);
}

static DEVI void gload16(const void* g, void* l) {
    __builtin_amdgcn_global_load_lds(
        (const __attribute__((address_space(1))) unsigned int*)g,
        (__attribute__((address_space(3))) unsigned int*)l,
        16, 0, 0);
}

// ---------------------------------------------------------------------------
// fp32 -> bf16 bulk convert (8 elems/thread)
// ---------------------------------------------------------------------------
__global__ __launch_bounds__(256)
void cvt_bf16(const float* __restrict__ in, short* __restrict__ out, int n8) {
    int i = blockIdx.x * 256 + threadIdx.x;
    if (i >= n8) return;
    const float4* p = (const float4*)in + (size_t)i * 2;
    float4 v0 = p[0], v1 = p[1];
    short r[8] = { f2bf(v0.x), f2bf(v0.y), f2bf(v0.z), f2bf(v0.w),
                   f2bf(v1.x), f2bf(v1.y), f2bf(v1.z), f2bf(v1.w) };
    *(uint4*)(out + (size_t)i * 8) = *(uint4*)r;
}

// ---------------------------------------------------------------------------
// NT GEMM, bf16 A,B: C[M,N] = A[M,K] * B[N,K]^T
// 128x128 tile, 4 waves (2x2) of 64x64, BK=32, mfma_f32_16x16x32_bf16.
// Staging: global_load_lds width=16, linear LDS [128][32] with 32B XOR swizzle
//   physical_chunk = logical_chunk ^ ((row&1)<<1)   (involution, both sides)
// ---------------------------------------------------------------------------
template<bool OUT_F32>
__global__ __launch_bounds__(256)
void gemm_bt(const short* __restrict__ A, const short* __restrict__ B,
             void* __restrict__ Cp, int M, int N, int K) {
    __shared__ short As[128 * 32];
    __shared__ short Bs[128 * 32];

    const int tid  = threadIdx.x;
    const int lane = tid & 63;
    const int wid  = tid >> 6;
    const int wr   = wid >> 1;
    const int wc   = wid & 1;
    const int brow = blockIdx.y * 128;
    const int bcol = blockIdx.x * 128;

    const int l15 = lane & 15;
    const int grp = lane >> 4;                    // k-chunk 0..3 for frag reads
    // staging lane mapping: LDS byte = chunkbase + lane*16
    const int sr = lane >> 2;                     // row within 16-row chunk
    const int sc = (lane & 3) ^ ((sr & 1) << 1);  // swizzled logical k-chunk

    f32x4 acc[4][4] = {};

    for (int k0 = 0; k0 < K; k0 += 32) {
        #pragma unroll
        for (int it = 0; it < 2; it++) {
            int cb = wid + it * 4;                // 16-row chunk index 0..7
            int r  = cb * 16 + sr;
            gload16(A + (size_t)(brow + r) * K + k0 + sc * 8, &As[cb * 512]);
            gload16(B + (size_t)(bcol + r) * K + k0 + sc * 8, &Bs[cb * 512]);
        }
        __syncthreads();                          // drains vmcnt -> LDS ready

        bf16x8 a[4], b[4];
        #pragma unroll
        for (int m = 0; m < 4; m++) {
            int rA = wr * 64 + m * 16 + l15;
            int ch = grp ^ ((rA & 1) << 1);
            a[m] = *(const bf16x8*)(&As[rA * 32 + ch * 8]);
        }
        #pragma unroll
        for (int n = 0; n < 4; n++) {
            int rB = wc * 64 + n * 16 + l15;
            int ch = grp ^ ((rB & 1) << 1);
            b[n] = *(const bf16x8*)(&Bs[rB * 32 + ch * 8]);
        }
        #pragma unroll
        for (int m = 0; m < 4; m++)
            #pragma unroll
            for (int n = 0; n < 4; n++)
                acc[m][n] = __builtin_amdgcn_mfma_f32_16x16x32_bf16(a[m], b[n], acc[m][n], 0, 0, 0);
        __syncthreads();
    }

    // C/D layout: col = lane&15, row = (lane>>4)*4 + j   (verified m89)
    const int r0 = brow + wr * 64 + (lane >> 4) * 4;
    const int c0 = bcol + wc * 64 + l15;
    if (OUT_F32) {
        float* C = (float*)Cp;
        #pragma unroll
        for (int m = 0; m < 4; m++)
            #pragma unroll
            for (int n = 0; n < 4; n++)
                #pragma unroll
                for (int j = 0; j < 4; j++)
                    C[(size_t)(r0 + m * 16 + j) * N + c0 + n * 16] = acc[m][n][j];
    } else {
        short* C = (short*)Cp;
        #pragma unroll
        for (int m = 0; m < 4; m++)
            #pragma unroll
            for (int n = 0; n < 4; n++)
                #pragma unroll
                for (int j = 0; j < 4; j++)
                    C[(size_t)(r0 + m * 16 + j) * N + c0 + n * 16] = f2bf(acc[m][n][j]);
    }
}

// ---------------------------------------------------------------------------
// Flash attention, 2 query sets per block (they share K/V).
//   block: blockIdx.x = b*32 + h*2 + gp  (gp picks g = gp*2 + {0,1})
//          blockIdx.y = q-tile (64 rows), 4 waves x 16 q-rows
//   K staged [kv][hd] vectorized; V^T staged [d][kv] via transposed global
//   gather (conflict-free LDS writes). Online softmax fp32.
// ---------------------------------------------------------------------------
__global__ __launch_bounds__(256)
void attn_fwd(const short* __restrict__ qkv, short* __restrict__ Y) {
    const int LDK = 72;                       // 144B rows, 16B-aligned, padded
    __shared__ short Ks[64 * 72];             // [kv][d]
    __shared__ short Vs[64 * 72];             // [d][kv]
    __shared__ short Ps[4][16 * 72];          // per-wave P [q][kv]

    const int tid  = threadIdx.x;
    const int lane = tid & 63;
    const int w    = tid >> 6;
    const int l15  = lane & 15;
    const int grp  = lane >> 4;
    const int g8   = grp * 8;

    const int combo = blockIdx.x;
    const int gp = combo & 1;
    const int h  = (combo >> 1) & 15;
    const int b  = combo >> 5;
    const int qt = blockIdx.y;
    const size_t RS = 6144;

    // Q A-frags for both query sets
    bf16x8 qf[2][2];
    #pragma unroll
    for (int gi = 0; gi < 2; gi++) {
        int g = gp * 2 + gi;
        const short* qp = qkv + (size_t)(b * 1024 + qt * 64 + w * 16 + l15) * RS
                          + g * 1024 + h * 64 + g8;
        qf[gi][0] = *(const bf16x8*)(qp);
        qf[gi][1] = *(const bf16x8*)(qp + 32);
    }

    f32x4 o[2][4] = {};
    float mrow[2][4], lrow[2][4];
    #pragma unroll
    for (int gi = 0; gi < 2; gi++)
        #pragma unroll
        for (int j = 0; j < 4; j++) { mrow[gi][j] = -1e30f; lrow[gi][j] = 0.f; }

    const int d2 = tid >> 3;                  // 0..31 (d-pair)
    const int ch = tid & 7;                   // kv chunk of 8

    for (int kvt = 0; kvt <= qt; kvt++) {
        __syncthreads();                      // prev-tile reads done
        // ---- stage K [kv][d], vectorized ----
        #pragma unroll
        for (int i = 0; i < 2; i++) {
            int idx = tid + i * 256;
            int r = idx >> 3, seg = idx & 7;
            const short* kp = qkv + (size_t)(b * 1024 + kvt * 64 + r) * RS
                              + 4096 + h * 64 + seg * 8;
            *(uint4*)(&Ks[r * LDK + seg * 8]) = *(const uint4*)kp;
        }
        // ---- stage V^T [d][kv] via transposed gather (uint = d-pair) ----
        {
            const short* vp = qkv + (size_t)(b * 1024 + kvt * 64 + ch * 8) * RS
                              + 5120 + h * 64 + d2 * 2;
            unsigned vv[8];
            #pragma unroll
            for (int j = 0; j < 8; j++)
                vv[j] = *(const unsigned*)(vp + (size_t)j * RS);
            unsigned lo[4], hi[4];
            #pragma unroll
            for (int j = 0; j < 4; j++) {
                lo[j] = (vv[2 * j] & 0xffffu) | (vv[2 * j + 1] << 16);
                hi[j] = (vv[2 * j] >> 16)     | (vv[2 * j + 1] & 0xffff0000u);
            }
            int d0 = d2 * 2;
            *(uint4*)(&Vs[d0 * LDK + ch * 8])       = *(uint4*)lo;
            *(uint4*)(&Vs[(d0 + 1) * LDK + ch * 8]) = *(uint4*)hi;
        }
        __syncthreads();

        // ---- S = QK^T * scale, both query sets share K-frags ----
        f32x4 s[2][4];
        #pragma unroll
        for (int c = 0; c < 4; c++) {
            f32x4 z0 = {}, z1 = {};
            #pragma unroll
            for (int ks = 0; ks < 2; ks++) {
                bf16x8 kb = *(const bf16x8*)(&Ks[(c * 16 + l15) * LDK + ks * 32 + g8]);
                z0 = __builtin_amdgcn_mfma_f32_16x16x32_bf16(qf[0][ks], kb, z0, 0, 0, 0);
                z1 = __builtin_amdgcn_mfma_f32_16x16x32_bf16(qf[1][ks], kb, z1, 0, 0, 0);
            }
            s[0][c] = z0 * 0.125f;
            s[1][c] = z1 * 0.125f;
        }

        const bool diag = (kvt == qt);
        short* pw = &Ps[w][0];

        #pragma unroll
        for (int gi = 0; gi < 2; gi++) {
            // causal mask (diagonal tile only)
            if (diag) {
                int qlo = w * 16 + grp * 4;           // tile-local q row base
                #pragma unroll
                for (int c = 0; c < 4; c++) {
                    int kvcol = c * 16 + l15;
                    #pragma unroll
                    for (int j = 0; j < 4; j++)
                        if (kvcol > qlo + j) s[gi][c][j] = -1e30f;
                }
            }
            // row max (over c in-lane, then 16-lane shuffle)
            float pm[4];
            #pragma unroll
            for (int j = 0; j < 4; j++)
                pm[j] = fmaxf(fmaxf(s[gi][0][j], s[gi][1][j]),
                              fmaxf(s[gi][2][j], s[gi][3][j]));
            #pragma unroll
            for (int off = 1; off < 16; off <<= 1)
                #pragma unroll
                for (int j = 0; j < 4; j++)
                    pm[j] = fmaxf(pm[j], __shfl_xor(pm[j], off));

            float alpha[4];
            #pragma unroll
            for (int j = 0; j < 4; j++) {
                float mn = fmaxf(mrow[gi][j], pm[j]);
                alpha[j] = __expf(mrow[gi][j] - mn);
                mrow[gi][j] = mn;
            }
            float psum[4] = {0.f, 0.f, 0.f, 0.f};
            #pragma unroll
            for (int c = 0; c < 4; c++)
                #pragma unroll
                for (int j = 0; j < 4; j++) {
                    float e = __expf(s[gi][c][j] - mrow[gi][j]);
                    s[gi][c][j] = e;
                    psum[j] += e;
                }
            #pragma unroll
            for (int off = 1; off < 16; off <<= 1)
                #pragma unroll
                for (int j = 0; j < 4; j++)
                    psum[j] += __shfl_xor(psum[j], off);
            #pragma unroll
            for (int j = 0; j < 4; j++)
                lrow[gi][j] = lrow[gi][j] * alpha[j] + psum[j];
            #pragma unroll
            for (int c = 0; c < 4; c++)
                #pragma unroll
                for (int j = 0; j < 4; j++)
                    o[gi][c][j] *= alpha[j];

            // P: C-layout -> A-layout via per-wave LDS (same-wave DS in order)
            #pragma unroll
            for (int c = 0; c < 4; c++)
                #pragma unroll
                for (int j = 0; j < 4; j++)
                    pw[(grp * 4 + j) * LDK + c * 16 + l15] = f2bf(s[gi][c][j]);

            // O += P V
            #pragma unroll
            for (int c2 = 0; c2 < 4; c2++)
                #pragma unroll
                for (int s2 = 0; s2 < 2; s2++) {
                    bf16x8 pa = *(const bf16x8*)(&pw[l15 * LDK + s2 * 32 + g8]);
                    bf16x8 vb = *(const bf16x8*)(&Vs[(c2 * 16 + l15) * LDK + s2 * 32 + g8]);
                    o[gi][c2] = __builtin_amdgcn_mfma_f32_16x16x32_bf16(pa, vb, o[gi][c2], 0, 0, 0);
                }
        }
    }

    // ---- epilogue ----
    const size_t yr0 = (size_t)(b * 1024 + qt * 64 + w * 16 + grp * 4);
    #pragma unroll
    for (int gi = 0; gi < 2; gi++) {
        int g = gp * 2 + gi;
        float inv[4];
        #pragma unroll
        for (int j = 0; j < 4; j++) inv[j] = 1.0f / lrow[gi][j];
        const int ycol0 = g * 1024 + h * 64 + l15;
        #pragma unroll
        for (int c2 = 0; c2 < 4; c2++)
            #pragma unroll
            for (int j = 0; j < 4; j++)
                Y[(yr0 + j) * 4096 + ycol0 + c2 * 16] = f2bf(o[gi][c2][j] * inv[j]);
    }
}

// ---------------------------------------------------------------------------
extern "C" void kernel_launch(void* const* d_in, const int* in_sizes, int n_in,
                              void* d_out, int out_size, void* d_ws, size_t ws_size,
                              hipStream_t stream) {
    const float* x  = (const float*)d_in[0];   // [8192,1024]
    const float* Wa = (const float*)d_in[1];   // [6144,1024]
    const float* Wp = (const float*)d_in[2];   // [1024,4096]
    float* out = (float*)d_out;

    short* qkv = (short*)d_ws;                        // 50331648 shorts
    short* Yb  = qkv + (size_t)8192 * 6144;           // 33554432 shorts
    short* xb  = Yb;                                  // pre-attn reuse of Yb
    short* Wab = Yb + (size_t)8192 * 1024;            // pre-attn reuse of Yb
    short* Wpb = qkv;                                 // post-attn reuse of qkv

    dim3 blk(256);
    // convert x, W_attn to bf16
    cvt_bf16<<<dim3(8192 * 1024 / 8 / 256), blk, 0, stream>>>(x, xb, 8192 * 1024 / 8);
    cvt_bf16<<<dim3(6144 * 1024 / 8 / 256), blk, 0, stream>>>(Wa, Wab, 6144 * 1024 / 8);
    // qkv = x @ W_attn^T   (M=8192, N=6144, K=1024)
    gemm_bt<false><<<dim3(48, 64), blk, 0, stream>>>(xb, Wab, (void*)qkv, 8192, 6144, 1024);
    // flash attention -> Y
    attn_fwd<<<dim3(256, 16), blk, 0, stream>>>(qkv, Yb);
    // convert W_proj, then out = Y @ W_proj^T   (M=8192, N=1024, K=4096)
    cvt_bf16<<<dim3(1024 * 4096 / 8 / 256), blk, 0, stream>>>(Wp, Wpb, 1024 * 4096 / 8);
    gemm_bt<true><<<dim3(8, 64), blk, 0, stream>>>(Yb, Wpb, (void*)out, 8192, 1024, 4096);
}

// Round 3
// 417.676 us; speedup vs baseline: 1.6969x; 1.2248x over previous
//
#include <hip/hip_runtime.h>

// ---------------------------------------------------------------------------
// CausalSelfAttention (GQA, 4 query sets sharing K/V)
//   B=8, T=1024, C=1024, H=16, hd=64, G=4
// Pipeline: cvt(x,Wa)->bf16, GEMM1 (gload_lds), attn v3 (swapped-QK^T 32x32,
// lane-local softmax, O^T accum, 4 qsets/block), cvt(Wp), GEMM2.
// ws layout (shorts):
//   qkv  [8192*6144] @ 0          (Wpb reuses first 4.2M after attn)
//   Yb   [8192*4096] @ 50331648   (xb, Wab live here before attn)
// ---------------------------------------------------------------------------

#define DEVI __device__ __forceinline__

typedef __attribute__((ext_vector_type(4)))  float f32x4;
typedef __attribute__((ext_vector_type(16))) float f32x16;
typedef __attribute__((ext_vector_type(8)))  short bf16x8;

static DEVI short f2bf(float f) {
    union { float f; unsigned int i; } c; c.f = f;
    unsigned int i = c.i;
    unsigned int r = i + 0x7FFFu + ((i >> 16) & 1u);   // RNE
    return (short)(r >> 16);
}

// truncating bf16 pair pack: low short = a, high short = b  (1 v_perm)
static DEVI unsigned pk2bf(float a, float b) {
    return __builtin_amdgcn_perm(__float_as_uint(b), __float_as_uint(a), 0x07060302u);
}

static DEVI void gload16(const void* g, void* l) {
    __builtin_amdgcn_global_load_lds(
        (const __attribute__((address_space(1))) unsigned int*)g,
        (__attribute__((address_space(3))) unsigned int*)l,
        16, 0, 0);
}

// ---------------------------------------------------------------------------
// fp32 -> bf16 bulk convert (8 elems/thread)
// ---------------------------------------------------------------------------
__global__ __launch_bounds__(256)
void cvt_bf16(const float* __restrict__ in, short* __restrict__ out, int n8) {
    int i = blockIdx.x * 256 + threadIdx.x;
    if (i >= n8) return;
    const float4* p = (const float4*)in + (size_t)i * 2;
    float4 v0 = p[0], v1 = p[1];
    short r[8] = { f2bf(v0.x), f2bf(v0.y), f2bf(v0.z), f2bf(v0.w),
                   f2bf(v1.x), f2bf(v1.y), f2bf(v1.z), f2bf(v1.w) };
    *(uint4*)(out + (size_t)i * 8) = *(uint4*)r;
}

// ---------------------------------------------------------------------------
// NT GEMM, bf16 A,B: C[M,N] = A[M,K] * B[N,K]^T  (unchanged from r2)
// ---------------------------------------------------------------------------
template<bool OUT_F32>
__global__ __launch_bounds__(256)
void gemm_bt(const short* __restrict__ A, const short* __restrict__ B,
             void* __restrict__ Cp, int M, int N, int K) {
    __shared__ short As[128 * 32];
    __shared__ short Bs[128 * 32];

    const int tid  = threadIdx.x;
    const int lane = tid & 63;
    const int wid  = tid >> 6;
    const int wr   = wid >> 1;
    const int wc   = wid & 1;
    const int brow = blockIdx.y * 128;
    const int bcol = blockIdx.x * 128;

    const int l15 = lane & 15;
    const int grp = lane >> 4;
    const int sr = lane >> 2;
    const int sc = (lane & 3) ^ ((sr & 1) << 1);

    f32x4 acc[4][4] = {};

    for (int k0 = 0; k0 < K; k0 += 32) {
        #pragma unroll
        for (int it = 0; it < 2; it++) {
            int cb = wid + it * 4;
            int r  = cb * 16 + sr;
            gload16(A + (size_t)(brow + r) * K + k0 + sc * 8, &As[cb * 512]);
            gload16(B + (size_t)(bcol + r) * K + k0 + sc * 8, &Bs[cb * 512]);
        }
        __syncthreads();

        bf16x8 a[4], b[4];
        #pragma unroll
        for (int m = 0; m < 4; m++) {
            int rA = wr * 64 + m * 16 + l15;
            int ch = grp ^ ((rA & 1) << 1);
            a[m] = *(const bf16x8*)(&As[rA * 32 + ch * 8]);
        }
        #pragma unroll
        for (int n = 0; n < 4; n++) {
            int rB = wc * 64 + n * 16 + l15;
            int ch = grp ^ ((rB & 1) << 1);
            b[n] = *(const bf16x8*)(&Bs[rB * 32 + ch * 8]);
        }
        #pragma unroll
        for (int m = 0; m < 4; m++)
            #pragma unroll
            for (int n = 0; n < 4; n++)
                acc[m][n] = __builtin_amdgcn_mfma_f32_16x16x32_bf16(a[m], b[n], acc[m][n], 0, 0, 0);
        __syncthreads();
    }

    const int r0 = brow + wr * 64 + (lane >> 4) * 4;
    const int c0 = bcol + wc * 64 + l15;
    if (OUT_F32) {
        float* C = (float*)Cp;
        #pragma unroll
        for (int m = 0; m < 4; m++)
            #pragma unroll
            for (int n = 0; n < 4; n++)
                #pragma unroll
                for (int j = 0; j < 4; j++)
                    C[(size_t)(r0 + m * 16 + j) * N + c0 + n * 16] = acc[m][n][j];
    } else {
        short* C = (short*)Cp;
        #pragma unroll
        for (int m = 0; m < 4; m++)
            #pragma unroll
            for (int n = 0; n < 4; n++)
                #pragma unroll
                for (int j = 0; j < 4; j++)
                    C[(size_t)(r0 + m * 16 + j) * N + c0 + n * 16] = f2bf(acc[m][n][j]);
    }
}

// ---------------------------------------------------------------------------
// Flash attention v3: swapped-QK^T 32x32, lane-local softmax, O^T accum.
//   block = 512 thr (8 waves), handles one (b,h) x q-tile(64) x ALL 4 qsets.
//   wave w: qset g=w>>1, local q rows (w&1)*32 + (lane&31).
//   S^T = mfma32x32x16(A=K, B=Q): lane q = lane&31, kv = 32*st + crow(r,hf)
//   O^T = mfma32x32x16(A=V^T, B=Pfrag): lane q = lane&31, d = 32*ds+crow(r,hf)
//   crow(r,hf) = (r&3) + 8*(r>>2) + 4*hf
//   LDS: Ks[64][64] + Vt[64][64] bf16 with chunk-XOR swizzle (T2);
//        epilogue reuses LDS as [256][34] u32 transpose buffer.
// ---------------------------------------------------------------------------
__global__ __launch_bounds__(512, 4)
void attn_fwd(const short* __restrict__ qkv, short* __restrict__ Y) {
    __shared__ __align__(16) char smem[34816];
    short* Ks = (short*)smem;            // [64 kv][8 chunk][8 bf16]
    short* Vt = (short*)smem + 4096;     // [64 d][8 chunk][8 bf16]

    const int tid  = threadIdx.x;
    const int lane = tid & 63;
    const int w    = tid >> 6;
    const int q    = lane & 31;          // lane's q column
    const int hf   = lane >> 5;          // half (0/1)

    const int b  = blockIdx.x >> 4;
    const int h  = blockIdx.x & 15;
    const int qt = (gridDim.y - 1) - blockIdx.y;   // reversed for load balance
    const int g  = w >> 1;
    const int lq = (w & 1) * 32 + q;     // local q row in [0,64)
    const size_t RS = 6144;
    const int bT = b * 1024;

    // ---- Q fragments (registers): qf[ks2] = Q[qrow][16*ks2 + 8*hf .. +8) ----
    bf16x8 qf[4];
    {
        const short* qp = qkv + (size_t)(bT + qt * 64 + lq) * RS + g * 1024 + h * 64 + 8 * hf;
        #pragma unroll
        for (int ks2 = 0; ks2 < 4; ks2++)
            qf[ks2] = *(const bf16x8*)(qp + 16 * ks2);
    }

    f32x16 ot[2] = {};                   // O^T accum: d = 32*dsub + crow(r,hf)
    float m_run = -3e38f, lsum = 0.f;

    // staging lane mappings
    const int kvS   = tid >> 3;                  // K stage: kv row
    const int klog  = (tid & 7) ^ (kvS & 7);     // inverse-swizzled source chunk
    const int d2    = tid >> 4;                  // V stage: d-pair 0..31
    const int ch4   = tid & 15;                  // V stage: 4-kv group
    const int vd0   = d2 * 2;

    for (int kvt = 0; kvt <= qt; kvt++) {
        __syncthreads();                 // prev-tile frag reads done
        // ---- stage K via global_load_lds (linear dest, pre-swizzled src) ----
        gload16(qkv + (size_t)(bT + kvt * 64 + kvS) * RS + 4096 + h * 64 + klog * 8,
                Ks + w * 512);
        // ---- stage V^T via transposed register gather (swizzled write) ----
        {
            const short* vp = qkv + (size_t)(bT + kvt * 64 + ch4 * 4) * RS + 5120 + h * 64 + vd0;
            unsigned v0 = *(const unsigned*)(vp);
            unsigned v1 = *(const unsigned*)(vp + RS);
            unsigned v2 = *(const unsigned*)(vp + 2 * RS);
            unsigned v3 = *(const unsigned*)(vp + 3 * RS);
            uint2 lo, hi2;
            lo.x  = __builtin_amdgcn_perm(v1, v0, 0x05040100u);
            lo.y  = __builtin_amdgcn_perm(v3, v2, 0x05040100u);
            hi2.x = __builtin_amdgcn_perm(v1, v0, 0x07060302u);
            hi2.y = __builtin_amdgcn_perm(v3, v2, 0x07060302u);
            char* vb = (char*)Vt;
            int p0 = (ch4 >> 1) ^ (vd0 & 7);
            int p1 = (ch4 >> 1) ^ ((vd0 + 1) & 7);
            *(uint2*)(vb + vd0 * 128 + p0 * 16 + (ch4 & 1) * 8)       = lo;
            *(uint2*)(vb + (vd0 + 1) * 128 + p1 * 16 + (ch4 & 1) * 8) = hi2;
        }
        __syncthreads();

        // ---- S^T = K Q^T (raw, scale folded into exp) ----
        f32x16 stt[2] = {};
        #pragma unroll
        for (int sti = 0; sti < 2; sti++) {
            const int kvr = sti * 32 + q;
            #pragma unroll
            for (int ks2 = 0; ks2 < 4; ks2++) {
                const int phys = (2 * ks2 + hf) ^ (kvr & 7);
                bf16x8 kf = *(const bf16x8*)(Ks + kvr * 64 + phys * 8);
                stt[sti] = __builtin_amdgcn_mfma_f32_32x32x16_bf16(kf, qf[ks2], stt[sti], 0, 0, 0);
            }
        }

        // ---- causal mask (diagonal tile only) ----
        if (kvt == qt) {
            #pragma unroll
            for (int sti = 0; sti < 2; sti++)
                #pragma unroll
                for (int r = 0; r < 16; r++) {
                    int kvl = sti * 32 + (r & 3) + 8 * (r >> 2) + 4 * hf;
                    if (kvl > lq) stt[sti][r] = -3e38f;
                }
        }

        // ---- lane-local online softmax (q = lane&31) ----
        float pm[4] = { -3e38f, -3e38f, -3e38f, -3e38f };
        #pragma unroll
        for (int r = 0; r < 16; r++)
            pm[r & 3] = fmaxf(pm[r & 3], fmaxf(stt[0][r], stt[1][r]));
        float mx = fmaxf(fmaxf(pm[0], pm[1]), fmaxf(pm[2], pm[3]));
        mx = fmaxf(mx, __shfl_xor(mx, 32));            // combine halves
        const float mn = fmaxf(m_run, mx);
        const float alpha = __expf((m_run - mn) * 0.125f);
        m_run = mn;
        const float ms = mn * 0.125f;
        float sp[4] = { 0.f, 0.f, 0.f, 0.f };
        #pragma unroll
        for (int sti = 0; sti < 2; sti++)
            #pragma unroll
            for (int r = 0; r < 16; r++) {
                float e = __expf(fmaf(stt[sti][r], 0.125f, -ms));
                stt[sti][r] = e;
                sp[r & 3] += e;
            }
        float sum = (sp[0] + sp[1]) + (sp[2] + sp[3]);
        sum += __shfl_xor(sum, 32);
        lsum = lsum * alpha + sum;
        ot[0] *= alpha;
        ot[1] *= alpha;

        // ---- P (f32, S^T layout) -> B-fragments for PV ----
        // frag ks elem j: kv = 16ks + 8hf + j; own regs r=8(ks&1)+4hf+jl,
        // partner supplies the other 4 (one shfl_xor(32) per word-pair).
        bf16x8 pf[4];
        #pragma unroll
        for (int ks = 0; ks < 4; ks++) {
            const int sti = ks >> 1, base = 8 * (ks & 1);
            unsigned X0 = pk2bf(stt[sti][base + 0], stt[sti][base + 1]);
            unsigned X1 = pk2bf(stt[sti][base + 2], stt[sti][base + 3]);
            unsigned Y0 = pk2bf(stt[sti][base + 4], stt[sti][base + 5]);
            unsigned Y1 = pk2bf(stt[sti][base + 6], stt[sti][base + 7]);
            unsigned r0 = (unsigned)__shfl_xor((int)(hf ? X0 : Y0), 32);
            unsigned r1 = (unsigned)__shfl_xor((int)(hf ? X1 : Y1), 32);
            unsigned t[4];
            t[0] = hf ? r0 : X0;  t[1] = hf ? r1 : X1;
            t[2] = hf ? Y0 : r0;  t[3] = hf ? Y1 : r1;
            pf[ks] = *(bf16x8*)t;
        }

        // ---- O^T += V^T P  (lane-local rescale already applied) ----
        #pragma unroll
        for (int dsub = 0; dsub < 2; dsub++) {
            const int dr = dsub * 32 + q;
            #pragma unroll
            for (int ks = 0; ks < 4; ks++) {
                const int phys = (2 * ks + hf) ^ (dr & 7);
                bf16x8 vf = *(const bf16x8*)(Vt + dr * 64 + phys * 8);
                ot[dsub] = __builtin_amdgcn_mfma_f32_32x32x16_bf16(vf, pf[ks], ot[dsub], 0, 0, 0);
            }
        }
    }

    // ---- epilogue: O^T -> LDS transpose -> coalesced Y writes ----
    __syncthreads();
    unsigned* obuf = (unsigned*)smem;            // [256 sq][34 dpair] u32
    const float inv = 1.0f / lsum;
    const int SQ = g * 64 + lq;
    #pragma unroll
    for (int dsub = 0; dsub < 2; dsub++)
        #pragma unroll
        for (int r = 0; r < 16; r += 2) {
            int d = dsub * 32 + (r & 3) + 8 * (r >> 2) + 4 * hf;
            unsigned pk = ((unsigned)(unsigned short)f2bf(ot[dsub][r] * inv)) |
                          (((unsigned)(unsigned short)f2bf(ot[dsub][r + 1] * inv)) << 16);
            obuf[SQ * 34 + (d >> 1)] = pk;
        }
    __syncthreads();
    {
        const int SQ2 = tid >> 1, seg = tid & 1;
        const int g2 = SQ2 >> 6, lq2 = SQ2 & 63;
        const size_t row = (size_t)(bT + qt * 64 + lq2);
        const unsigned* src = obuf + SQ2 * 34 + seg * 16;
        unsigned* dst = (unsigned*)(Y + row * 4096 + g2 * 1024 + h * 64 + seg * 32);
        #pragma unroll
        for (int k = 0; k < 4; k++) {
            uint2 u0 = *(const uint2*)(src + 4 * k);
            uint2 u1 = *(const uint2*)(src + 4 * k + 2);
            uint4 t; t.x = u0.x; t.y = u0.y; t.z = u1.x; t.w = u1.y;
            *(uint4*)(dst + 4 * k) = t;
        }
    }
}

// ---------------------------------------------------------------------------
extern "C" void kernel_launch(void* const* d_in, const int* in_sizes, int n_in,
                              void* d_out, int out_size, void* d_ws, size_t ws_size,
                              hipStream_t stream) {
    const float* x  = (const float*)d_in[0];   // [8192,1024]
    const float* Wa = (const float*)d_in[1];   // [6144,1024]
    const float* Wp = (const float*)d_in[2];   // [1024,4096]
    float* out = (float*)d_out;

    short* qkv = (short*)d_ws;                        // 50331648 shorts
    short* Yb  = qkv + (size_t)8192 * 6144;           // 33554432 shorts
    short* xb  = Yb;                                  // pre-attn reuse of Yb
    short* Wab = Yb + (size_t)8192 * 1024;            // pre-attn reuse of Yb
    short* Wpb = qkv;                                 // post-attn reuse of qkv

    dim3 blk(256);
    cvt_bf16<<<dim3(8192 * 1024 / 8 / 256), blk, 0, stream>>>(x, xb, 8192 * 1024 / 8);
    cvt_bf16<<<dim3(6144 * 1024 / 8 / 256), blk, 0, stream>>>(Wa, Wab, 6144 * 1024 / 8);
    // qkv = x @ W_attn^T   (M=8192, N=6144, K=1024)
    gemm_bt<false><<<dim3(48, 64), blk, 0, stream>>>(xb, Wab, (void*)qkv, 8192, 6144, 1024);
    // flash attention -> Y   (128 combos x 16 q-tiles, 512 thr)
    attn_fwd<<<dim3(128, 16), dim3(512), 0, stream>>>(qkv, Yb);
    // out = Y @ W_proj^T   (M=8192, N=1024, K=4096)
    cvt_bf16<<<dim3(1024 * 4096 / 8 / 256), blk, 0, stream>>>(Wp, Wpb, 1024 * 4096 / 8);
    gemm_bt<true><<<dim3(8, 64), blk, 0, stream>>>(Yb, Wpb, (void*)out, 8192, 1024, 4096);
}

// Round 4
// 400.463 us; speedup vs baseline: 1.7698x; 1.0430x over previous
//
#include <hip/hip_runtime.h>

// ---------------------------------------------------------------------------
// CausalSelfAttention (GQA, 4 query sets sharing K/V)
//   B=8, T=1024, C=1024, H=16, hd=64, G=4
// Pipeline: cvt(x,Wa[Q-rows prescaled by 0.125*log2e])->bf16, GEMM1,
// attn v4 (swapped-QK^T 32x32, exp2 softmax, permlane pack, defer-max,
// double-buffered prefetch), cvt(Wp), GEMM2.
// ws layout (shorts):
//   qkv  [8192*6144] @ 0          (Wpb reuses first 4.2M after attn)
//   Yb   [8192*4096] @ 50331648   (xb, Wab live here before attn)
// ---------------------------------------------------------------------------

#define DEVI __device__ __forceinline__

typedef __attribute__((ext_vector_type(4)))  float f32x4;
typedef __attribute__((ext_vector_type(16))) float f32x16;
typedef __attribute__((ext_vector_type(8)))  short bf16x8;

static DEVI short f2bf(float f) {
    union { float f; unsigned int i; } c; c.f = f;
    unsigned int i = c.i;
    unsigned int r = i + 0x7FFFu + ((i >> 16) & 1u);   // RNE
    return (short)(r >> 16);
}

// truncating bf16 pair pack: low short = a, high short = b  (1 v_perm)
static DEVI unsigned pk2bf(float a, float b) {
    return __builtin_amdgcn_perm(__float_as_uint(b), __float_as_uint(a), 0x07060302u);
}

static DEVI void gload16(const void* g, void* l) {
    __builtin_amdgcn_global_load_lds(
        (const __attribute__((address_space(1))) unsigned int*)g,
        (__attribute__((address_space(3))) unsigned int*)l,
        16, 0, 0);
}

// ---------------------------------------------------------------------------
// fp32 -> bf16 bulk convert (8 elems/thread), optional scale
// ---------------------------------------------------------------------------
__global__ __launch_bounds__(256)
void cvt_bf16(const float* __restrict__ in, short* __restrict__ out, int n8,
              float scale) {
    int i = blockIdx.x * 256 + threadIdx.x;
    if (i >= n8) return;
    const float4* p = (const float4*)in + (size_t)i * 2;
    float4 v0 = p[0], v1 = p[1];
    short r[8] = { f2bf(v0.x * scale), f2bf(v0.y * scale),
                   f2bf(v0.z * scale), f2bf(v0.w * scale),
                   f2bf(v1.x * scale), f2bf(v1.y * scale),
                   f2bf(v1.z * scale), f2bf(v1.w * scale) };
    *(uint4*)(out + (size_t)i * 8) = *(uint4*)r;
}

// ---------------------------------------------------------------------------
// NT GEMM, bf16 A,B: C[M,N] = A[M,K] * B[N,K]^T  (unchanged from r2)
// ---------------------------------------------------------------------------
template<bool OUT_F32>
__global__ __launch_bounds__(256)
void gemm_bt(const short* __restrict__ A, const short* __restrict__ B,
             void* __restrict__ Cp, int M, int N, int K) {
    __shared__ short As[128 * 32];
    __shared__ short Bs[128 * 32];

    const int tid  = threadIdx.x;
    const int lane = tid & 63;
    const int wid  = tid >> 6;
    const int wr   = wid >> 1;
    const int wc   = wid & 1;
    const int brow = blockIdx.y * 128;
    const int bcol = blockIdx.x * 128;

    const int l15 = lane & 15;
    const int grp = lane >> 4;
    const int sr = lane >> 2;
    const int sc = (lane & 3) ^ ((sr & 1) << 1);

    f32x4 acc[4][4] = {};

    for (int k0 = 0; k0 < K; k0 += 32) {
        #pragma unroll
        for (int it = 0; it < 2; it++) {
            int cb = wid + it * 4;
            int r  = cb * 16 + sr;
            gload16(A + (size_t)(brow + r) * K + k0 + sc * 8, &As[cb * 512]);
            gload16(B + (size_t)(bcol + r) * K + k0 + sc * 8, &Bs[cb * 512]);
        }
        __syncthreads();

        bf16x8 a[4], b[4];
        #pragma unroll
        for (int m = 0; m < 4; m++) {
            int rA = wr * 64 + m * 16 + l15;
            int ch = grp ^ ((rA & 1) << 1);
            a[m] = *(const bf16x8*)(&As[rA * 32 + ch * 8]);
        }
        #pragma unroll
        for (int n = 0; n < 4; n++) {
            int rB = wc * 64 + n * 16 + l15;
            int ch = grp ^ ((rB & 1) << 1);
            b[n] = *(const bf16x8*)(&Bs[rB * 32 + ch * 8]);
        }
        #pragma unroll
        for (int m = 0; m < 4; m++)
            #pragma unroll
            for (int n = 0; n < 4; n++)
                acc[m][n] = __builtin_amdgcn_mfma_f32_16x16x32_bf16(a[m], b[n], acc[m][n], 0, 0, 0);
        __syncthreads();
    }

    const int r0 = brow + wr * 64 + (lane >> 4) * 4;
    const int c0 = bcol + wc * 64 + l15;
    if (OUT_F32) {
        float* C = (float*)Cp;
        #pragma unroll
        for (int m = 0; m < 4; m++)
            #pragma unroll
            for (int n = 0; n < 4; n++)
                #pragma unroll
                for (int j = 0; j < 4; j++)
                    C[(size_t)(r0 + m * 16 + j) * N + c0 + n * 16] = acc[m][n][j];
    } else {
        short* C = (short*)Cp;
        #pragma unroll
        for (int m = 0; m < 4; m++)
            #pragma unroll
            for (int n = 0; n < 4; n++)
                #pragma unroll
                for (int j = 0; j < 4; j++)
                    C[(size_t)(r0 + m * 16 + j) * N + c0 + n * 16] = f2bf(acc[m][n][j]);
    }
}

// ---------------------------------------------------------------------------
// Flash attention v4: swapped-QK^T 32x32, lane-local exp2 softmax, O^T accum,
// double-buffered K/V prefetch (one barrier per tile), permlane32 pack,
// defer-max, setprio.
//   block = 512 thr (8 waves): one (b,h) x q-tile(64) x ALL 4 qsets.
//   S'^T = K (Q*s)^T with s = 0.125*log2e folded into W_attn Q rows.
//   LDS: Ks[2]/Vt[2] 8KB each (32KB), epilogue reuse as [256][34] u32.
// ---------------------------------------------------------------------------
__global__ __launch_bounds__(512, 4)
void attn_fwd(const short* __restrict__ qkv, short* __restrict__ Y) {
    __shared__ __align__(16) char smem[34816];
    short* const KsB0 = (short*)smem;            // [64 kv][8 chunk][8 bf16]
    short* const VtB0 = (short*)smem + 4096;     // [64 d][8 chunk][8 bf16]
    short* const KsB1 = (short*)smem + 8192;
    short* const VtB1 = (short*)smem + 12288;

    const int tid  = threadIdx.x;
    const int lane = tid & 63;
    const int w    = tid >> 6;
    const int q    = lane & 31;          // lane's q column
    const int hf   = lane >> 5;          // half (0/1)

    const int b  = blockIdx.x >> 4;
    const int h  = blockIdx.x & 15;
    const int qt = (gridDim.y - 1) - blockIdx.y;   // reversed for load balance
    const int g  = w >> 1;
    const int lq = (w & 1) * 32 + q;     // local q row in [0,64)
    const size_t RS = 6144;
    const int bT = b * 1024;

    // ---- Q fragments (pre-scaled by 0.125*log2e via W_attn) ----
    bf16x8 qf[4];
    {
        const short* qp = qkv + (size_t)(bT + qt * 64 + lq) * RS + g * 1024 + h * 64 + 8 * hf;
        #pragma unroll
        for (int ks2 = 0; ks2 < 4; ks2++)
            qf[ks2] = *(const bf16x8*)(qp + 16 * ks2);
    }

    f32x16 ot[2] = {};                   // O^T accum: d = 32*dsub + crow(r,hf)
    float m_run = -3e38f, lsum = 0.f;

    // staging lane mappings
    const int kvS   = tid >> 3;                  // K stage: kv row
    const int klog  = (tid & 7) ^ (kvS & 7);     // inverse-swizzled source chunk
    const int d2    = tid >> 4;                  // V stage: d-pair 0..31
    const int ch4   = tid & 15;                  // V stage: 4-kv group
    const int vd0   = d2 * 2;
    const int vp0   = (ch4 >> 1) ^ (vd0 & 7);
    const int vp1   = (ch4 >> 1) ^ ((vd0 + 1) & 7);

    const short* const kvtile = qkv + (size_t)bT * RS + h * 64;

    // ---- prologue: stage tile 0 into buf0 ----
    {
        const short* vp = kvtile + (size_t)(ch4 * 4) * RS + 5120 + vd0;
        unsigned v0 = *(const unsigned*)(vp);
        unsigned v1 = *(const unsigned*)(vp + RS);
        unsigned v2 = *(const unsigned*)(vp + 2 * RS);
        unsigned v3 = *(const unsigned*)(vp + 3 * RS);
        gload16(kvtile + (size_t)kvS * RS + 4096 + klog * 8, KsB0 + w * 512);
        uint2 lo, hi2;
        lo.x  = __builtin_amdgcn_perm(v1, v0, 0x05040100u);
        lo.y  = __builtin_amdgcn_perm(v3, v2, 0x05040100u);
        hi2.x = __builtin_amdgcn_perm(v1, v0, 0x07060302u);
        hi2.y = __builtin_amdgcn_perm(v3, v2, 0x07060302u);
        char* vb = (char*)VtB0;
        *(uint2*)(vb + vd0 * 128 + vp0 * 16 + (ch4 & 1) * 8)       = lo;
        *(uint2*)(vb + (vd0 + 1) * 128 + vp1 * 16 + (ch4 & 1) * 8) = hi2;
    }
    __syncthreads();                      // buf0 ready (drains vmcnt+lgkm)

    for (int kvt = 0; kvt <= qt; kvt++) {
        short* const Ksc = (kvt & 1) ? KsB1 : KsB0;
        short* const Vtc = (kvt & 1) ? VtB1 : VtB0;
        short* const Ksn = (kvt & 1) ? KsB0 : KsB1;
        short* const Vtn = (kvt & 1) ? VtB0 : VtB1;
        const bool pf = (kvt < qt);

        // ---- issue next-tile loads (hidden under this tile's compute) ----
        unsigned v0, v1, v2, v3;
        if (pf) {
            const short* vp = kvtile + (size_t)((kvt + 1) * 64 + ch4 * 4) * RS + 5120 + vd0;
            v0 = *(const unsigned*)(vp);
            v1 = *(const unsigned*)(vp + RS);
            v2 = *(const unsigned*)(vp + 2 * RS);
            v3 = *(const unsigned*)(vp + 3 * RS);
            gload16(kvtile + (size_t)((kvt + 1) * 64 + kvS) * RS + 4096 + klog * 8,
                    Ksn + w * 512);
        }

        // ---- S'^T = K Q'^T (already log2-scaled) ----
        f32x16 stt[2] = {};
        __builtin_amdgcn_s_setprio(1);
        #pragma unroll
        for (int sti = 0; sti < 2; sti++) {
            const int kvr = sti * 32 + q;
            #pragma unroll
            for (int ks2 = 0; ks2 < 4; ks2++) {
                const int phys = (2 * ks2 + hf) ^ (kvr & 7);
                bf16x8 kf = *(const bf16x8*)(Ksc + kvr * 64 + phys * 8);
                stt[sti] = __builtin_amdgcn_mfma_f32_32x32x16_bf16(kf, qf[ks2], stt[sti], 0, 0, 0);
            }
        }
        __builtin_amdgcn_s_setprio(0);

        // ---- causal mask (diagonal tile only) ----
        if (kvt == qt) {
            #pragma unroll
            for (int sti = 0; sti < 2; sti++)
                #pragma unroll
                for (int r = 0; r < 16; r++) {
                    int kvl = sti * 32 + (r & 3) + 8 * (r >> 2) + 4 * hf;
                    if (kvl > lq) stt[sti][r] = -3e38f;
                }
        }

        // ---- lane-local online softmax (exp2 domain) ----
        float pm[4] = { -3e38f, -3e38f, -3e38f, -3e38f };
        #pragma unroll
        for (int r = 0; r < 16; r++)
            pm[r & 3] = fmaxf(pm[r & 3], fmaxf(stt[0][r], stt[1][r]));
        float mx = fmaxf(fmaxf(pm[0], pm[1]), fmaxf(pm[2], pm[3]));
        mx = fmaxf(mx, __shfl_xor(mx, 32));            // combine halves

        if (!__all(mx - m_run <= 8.0f)) {              // defer-max (T13)
            const float mn = fmaxf(m_run, mx);
            const float alpha = __builtin_amdgcn_exp2f(m_run - mn);
            m_run = mn;
            lsum *= alpha;
            ot[0] *= alpha;
            ot[1] *= alpha;
        }

        float sp[4] = { 0.f, 0.f, 0.f, 0.f };
        #pragma unroll
        for (int sti = 0; sti < 2; sti++)
            #pragma unroll
            for (int r = 0; r < 16; r++) {
                float e = __builtin_amdgcn_exp2f(stt[sti][r] - m_run);
                stt[sti][r] = e;
                sp[r & 3] += e;
            }
        float sum = (sp[0] + sp[1]) + (sp[2] + sp[3]);
        sum += __shfl_xor(sum, 32);
        lsum += sum;

        // ---- write next-tile V^T (waits only the 4 gather dwords) ----
        if (pf) {
            uint2 lo, hi2;
            lo.x  = __builtin_amdgcn_perm(v1, v0, 0x05040100u);
            lo.y  = __builtin_amdgcn_perm(v3, v2, 0x05040100u);
            hi2.x = __builtin_amdgcn_perm(v1, v0, 0x07060302u);
            hi2.y = __builtin_amdgcn_perm(v3, v2, 0x07060302u);
            char* vb = (char*)Vtn;
            *(uint2*)(vb + vd0 * 128 + vp0 * 16 + (ch4 & 1) * 8)       = lo;
            *(uint2*)(vb + (vd0 + 1) * 128 + vp1 * 16 + (ch4 & 1) * 8) = hi2;
        }

        // ---- P -> B-fragments: t0={X0lo,Y0lo}, t2={X0hi,Y0hi} via permlane ----
        bf16x8 pf4[4];
        #pragma unroll
        for (int ks = 0; ks < 4; ks++) {
            const int sti = ks >> 1, base = 8 * (ks & 1);
            unsigned X0 = pk2bf(stt[sti][base + 0], stt[sti][base + 1]);
            unsigned X1 = pk2bf(stt[sti][base + 2], stt[sti][base + 3]);
            unsigned Y0 = pk2bf(stt[sti][base + 4], stt[sti][base + 5]);
            unsigned Y1 = pk2bf(stt[sti][base + 6], stt[sti][base + 7]);
            asm("v_permlane32_swap_b32 %0, %1" : "+v"(X0), "+v"(Y0));
            asm("v_permlane32_swap_b32 %0, %1" : "+v"(X1), "+v"(Y1));
            unsigned t[4] = { X0, X1, Y0, Y1 };
            pf4[ks] = *(bf16x8*)t;
        }

        // ---- O^T += V^T P ----
        __builtin_amdgcn_s_setprio(1);
        #pragma unroll
        for (int dsub = 0; dsub < 2; dsub++) {
            const int dr = dsub * 32 + q;
            #pragma unroll
            for (int ks = 0; ks < 4; ks++) {
                const int phys = (2 * ks + hf) ^ (dr & 7);
                bf16x8 vf = *(const bf16x8*)(Vtc + dr * 64 + phys * 8);
                ot[dsub] = __builtin_amdgcn_mfma_f32_32x32x16_bf16(vf, pf4[ks], ot[dsub], 0, 0, 0);
            }
        }
        __builtin_amdgcn_s_setprio(0);

        __syncthreads();     // drains prefetch vmcnt + V writes; buffers swap
    }

    // ---- epilogue: O^T -> LDS transpose -> coalesced Y writes ----
    unsigned* obuf = (unsigned*)smem;            // [256 sq][34 dpair] u32
    const float inv = 1.0f / lsum;
    const int SQ = g * 64 + lq;
    #pragma unroll
    for (int dsub = 0; dsub < 2; dsub++)
        #pragma unroll
        for (int r = 0; r < 16; r += 2) {
            int d = dsub * 32 + (r & 3) + 8 * (r >> 2) + 4 * hf;
            unsigned pk = ((unsigned)(unsigned short)f2bf(ot[dsub][r] * inv)) |
                          (((unsigned)(unsigned short)f2bf(ot[dsub][r + 1] * inv)) << 16);
            obuf[SQ * 34 + (d >> 1)] = pk;
        }
    __syncthreads();
    {
        const int SQ2 = tid >> 1, seg = tid & 1;
        const int g2 = SQ2 >> 6, lq2 = SQ2 & 63;
        const size_t row = (size_t)(bT + qt * 64 + lq2);
        const unsigned* src = obuf + SQ2 * 34 + seg * 16;
        unsigned* dst = (unsigned*)(Y + row * 4096 + g2 * 1024 + h * 64 + seg * 32);
        #pragma unroll
        for (int k = 0; k < 4; k++) {
            uint2 u0 = *(const uint2*)(src + 4 * k);
            uint2 u1 = *(const uint2*)(src + 4 * k + 2);
            uint4 t; t.x = u0.x; t.y = u0.y; t.z = u1.x; t.w = u1.y;
            *(uint4*)(dst + 4 * k) = t;
        }
    }
}

// ---------------------------------------------------------------------------
extern "C" void kernel_launch(void* const* d_in, const int* in_sizes, int n_in,
                              void* d_out, int out_size, void* d_ws, size_t ws_size,
                              hipStream_t stream) {
    const float* x  = (const float*)d_in[0];   // [8192,1024]
    const float* Wa = (const float*)d_in[1];   // [6144,1024]
    const float* Wp = (const float*)d_in[2];   // [1024,4096]
    float* out = (float*)d_out;

    short* qkv = (short*)d_ws;                        // 50331648 shorts
    short* Yb  = qkv + (size_t)8192 * 6144;           // 33554432 shorts
    short* xb  = Yb;                                  // pre-attn reuse of Yb
    short* Wab = Yb + (size_t)8192 * 1024;            // pre-attn reuse of Yb
    short* Wpb = qkv;                                 // post-attn reuse of qkv

    const float QS = 0.18033688011112042f;            // 0.125 * log2(e)
    dim3 blk(256);
    cvt_bf16<<<dim3(8192 * 1024 / 8 / 256), blk, 0, stream>>>(x, xb, 8192 * 1024 / 8, 1.0f);
    // W_attn: Q rows scaled into exp2 domain, K/V rows unscaled
    cvt_bf16<<<dim3(4096 * 1024 / 8 / 256), blk, 0, stream>>>(Wa, Wab, 4096 * 1024 / 8, QS);
    cvt_bf16<<<dim3(2048 * 1024 / 8 / 256), blk, 0, stream>>>(
        Wa + (size_t)4096 * 1024, Wab + (size_t)4096 * 1024, 2048 * 1024 / 8, 1.0f);
    // qkv = x @ W_attn^T   (M=8192, N=6144, K=1024)
    gemm_bt<false><<<dim3(48, 64), blk, 0, stream>>>(xb, Wab, (void*)qkv, 8192, 6144, 1024);
    // flash attention -> Y   (128 combos x 16 q-tiles, 512 thr)
    attn_fwd<<<dim3(128, 16), dim3(512), 0, stream>>>(qkv, Yb);
    // out = Y @ W_proj^T   (M=8192, N=1024, K=4096)
    cvt_bf16<<<dim3(1024 * 4096 / 8 / 256), blk, 0, stream>>>(Wp, Wpb, 1024 * 4096 / 8, 1.0f);
    gemm_bt<true><<<dim3(8, 64), blk, 0, stream>>>(Yb, Wpb, (void*)out, 8192, 1024, 4096);
}

// Round 5
// 370.826 us; speedup vs baseline: 1.9113x; 1.0799x over previous
//
#include <hip/hip_runtime.h>

// ---------------------------------------------------------------------------
// CausalSelfAttention (GQA, 4 query sets sharing K/V)
//   B=8, T=1024, C=1024, H=16, hd=64, G=4
// Pipeline: cvt(x,Wa[Q prescaled])->bf16, GEMM1 = 256^2 8-phase template,
// attn v4 (swapped-QK^T, exp2, permlane, defer-max, dbuf prefetch),
// cvt(Wp), GEMM2 = 128^2 gload_lds kernel.
// ws layout (shorts):
//   qkv  [8192*6144] @ 0          (Wpb reuses first 4.2M after attn)
//   Yb   [8192*4096] @ 50331648   (xb, Wab live here before attn)
// ---------------------------------------------------------------------------

#define DEVI __device__ __forceinline__

typedef __attribute__((ext_vector_type(4)))  float f32x4;
typedef __attribute__((ext_vector_type(16))) float f32x16;
typedef __attribute__((ext_vector_type(8)))  short bf16x8;

static DEVI short f2bf(float f) {
    union { float f; unsigned int i; } c; c.f = f;
    unsigned int i = c.i;
    unsigned int r = i + 0x7FFFu + ((i >> 16) & 1u);   // RNE
    return (short)(r >> 16);
}

static DEVI unsigned pk2bf(float a, float b) {
    return __builtin_amdgcn_perm(__float_as_uint(b), __float_as_uint(a), 0x07060302u);
}

static DEVI void gload16(const void* g, void* l) {
    __builtin_amdgcn_global_load_lds(
        (const __attribute__((address_space(1))) unsigned int*)g,
        (__attribute__((address_space(3))) unsigned int*)l,
        16, 0, 0);
}

#define BARRIER() do { __builtin_amdgcn_s_barrier(); \
                       __builtin_amdgcn_sched_barrier(0); } while (0)
#define WAITVM(n) do { asm volatile("s_waitcnt vmcnt(%0)" :: "i"(n) : "memory"); \
                       __builtin_amdgcn_sched_barrier(0); } while (0)

// ---------------------------------------------------------------------------
// fp32 -> bf16 bulk convert (8 elems/thread), optional scale
// ---------------------------------------------------------------------------
__global__ __launch_bounds__(256)
void cvt_bf16(const float* __restrict__ in, short* __restrict__ out, int n8,
              float scale) {
    int i = blockIdx.x * 256 + threadIdx.x;
    if (i >= n8) return;
    const float4* p = (const float4*)in + (size_t)i * 2;
    float4 v0 = p[0], v1 = p[1];
    short r[8] = { f2bf(v0.x * scale), f2bf(v0.y * scale),
                   f2bf(v0.z * scale), f2bf(v0.w * scale),
                   f2bf(v1.x * scale), f2bf(v1.y * scale),
                   f2bf(v1.z * scale), f2bf(v1.w * scale) };
    *(uint4*)(out + (size_t)i * 8) = *(uint4*)r;
}

// ---------------------------------------------------------------------------
// GEMM1: 256x256 tile, BK=64, 8-phase schedule (T2+T3+T4+T5+T1).
//   C[M,N] = A[M,K] * B[N,K]^T, all bf16, C bf16.
//   8 waves (2M x 4N), per-wave 128x64 output = 8x4 16x16 frags.
//   LDS 128KB: A[2bufs][2halves][128r][64c] + B same. st_16x32 swizzle:
//   physical chunk(8 bf16) = logical ^ (((row>>2)&1)<<1), applied
//   inverse-on-global-source (linear gload_lds dest) + forward-on-read.
//   Staging: A-h0(u+1)@ph0, A-h1(u+1)@ph1, B-h0(u+2)@ph2, B-h1(u+2)@ph3.
//   Liveness: A halves of a buffer last read at ph2 of the tile 2 earlier;
//   B halves last read at ph1 of the current tile -> all stages write dead
//   regions. vmcnt(4) at tile end leaves exactly B(u+2) in flight.
// ---------------------------------------------------------------------------
static DEVI void stage_half(const short* __restrict__ G, int ldg,
                            short* ldsHalf, int tid) {
    #pragma unroll
    for (int i = 0; i < 2; ++i) {
        int c = tid + (i << 9);                       // chunk 0..1023
        int row = c >> 3;
        int k8 = (c & 7) ^ (((row >> 2) & 1) << 1);   // inverse swizzle on src
        gload16(G + (size_t)row * ldg + k8 * 8, ldsHalf + ((c >> 6) << 9));
    }
}

static DEVI bf16x8 ldsfrag(const short* half, int lr, int k8r) {
    int off = lr * 64 + ((k8r * 8) ^ (((lr >> 2) & 1) << 4));
    return *(const bf16x8*)(half + off);
}

__global__ __launch_bounds__(512)
void gemm8_bt(const short* __restrict__ A, const short* __restrict__ B,
              short* __restrict__ C, int M, int N, int K, int nwgN) {
    __shared__ short lds[65536];                      // 128 KB
    short* const ldsA = lds;                          // [2][2][8192]
    short* const ldsB = lds + 32768;

    const int tid  = threadIdx.x;
    const int lane = tid & 63;
    const int w    = tid >> 6;
    const int wr   = w >> 2;                          // 0..1
    const int wc   = w & 3;                           // 0..3
    const int l15  = lane & 15;
    const int g4   = lane >> 4;

    const int nwg = gridDim.x;                        // multiple of 8
    const int wg  = blockIdx.x;
    const int swz = (wg & 7) * (nwg >> 3) + (wg >> 3);
    const int tm  = swz / nwgN, tn = swz % nwgN;

    const short* Ag = A + (size_t)tm * 256 * K;
    const short* Bg = B + (size_t)tn * 256 * K;
    const int NT = K >> 6;

    f32x4 acc[8][4] = {};

    // ---- prologue: A(0)h0,h1  B(0)h0,h1  B(1)h0,h1 ----
    stage_half(Ag,                      K, ldsA,               tid);
    stage_half(Ag + (size_t)128 * K,    K, ldsA + 8192,        tid);
    stage_half(Bg,                      K, ldsB,               tid);
    stage_half(Bg + (size_t)128 * K,    K, ldsB + 8192,        tid);
    stage_half(Bg + 64,                 K, ldsB + 16384,       tid);
    stage_half(Bg + (size_t)128 * K + 64, K, ldsB + 16384 + 8192, tid);
    WAITVM(4);                                        // tile0 fully landed
    BARRIER();

    for (int u = 0; u < NT; ++u) {
        const int buf = u & 1;
        const short* Ah = ldsA + buf * 16384 + wr * 8192;
        const short* Bh = ldsB + buf * 16384 + (wc >> 1) * 8192;
        const int lrB = (wc & 1) * 64;
        short* stA = ldsA + (buf ^ 1) * 16384;        // tile u+1
        short* stB = ldsB + buf * 16384;              // tile u+2 (same buf)
        const short* AgN  = Ag + (size_t)(u + 1) * 64;
        const short* BgN2 = Bg + (size_t)(u + 2) * 64;
        const bool doA = (u + 1 < NT), doB = (u + 2 < NT);

        bf16x8 af[4][2], b0[2][2], b1[2][2];

        // ---------- phase 0: (mh0, nh0) ----------
        #pragma unroll
        for (int f = 0; f < 4; ++f)
            #pragma unroll
            for (int ks = 0; ks < 2; ++ks)
                af[f][ks] = ldsfrag(Ah, f * 16 + l15, ks * 4 + g4);
        #pragma unroll
        for (int fn = 0; fn < 2; ++fn)
            #pragma unroll
            for (int ks = 0; ks < 2; ++ks)
                b0[fn][ks] = ldsfrag(Bh, lrB + fn * 16 + l15, ks * 4 + g4);
        if (doA) stage_half(AgN, K, stA, tid);
        BARRIER();
        __builtin_amdgcn_s_setprio(1);
        #pragma unroll
        for (int f = 0; f < 4; ++f)
            #pragma unroll
            for (int fn = 0; fn < 2; ++fn)
                #pragma unroll
                for (int ks = 0; ks < 2; ++ks)
                    acc[f][fn] = __builtin_amdgcn_mfma_f32_16x16x32_bf16(
                        af[f][ks], b0[fn][ks], acc[f][fn], 0, 0, 0);
        __builtin_amdgcn_s_setprio(0);
        BARRIER();

        // ---------- phase 1: (mh0, nh1) ----------
        #pragma unroll
        for (int fn = 0; fn < 2; ++fn)
            #pragma unroll
            for (int ks = 0; ks < 2; ++ks)
                b1[fn][ks] = ldsfrag(Bh, lrB + 32 + fn * 16 + l15, ks * 4 + g4);
        if (doA) stage_half(AgN + (size_t)128 * K, K, stA + 8192, tid);
        BARRIER();
        __builtin_amdgcn_s_setprio(1);
        #pragma unroll
        for (int f = 0; f < 4; ++f)
            #pragma unroll
            for (int fn = 0; fn < 2; ++fn)
                #pragma unroll
                for (int ks = 0; ks < 2; ++ks)
                    acc[f][2 + fn] = __builtin_amdgcn_mfma_f32_16x16x32_bf16(
                        af[f][ks], b1[fn][ks], acc[f][2 + fn], 0, 0, 0);
        __builtin_amdgcn_s_setprio(0);
        BARRIER();

        // ---------- phase 2: (mh1, nh0) ----------
        #pragma unroll
        for (int f = 0; f < 4; ++f)
            #pragma unroll
            for (int ks = 0; ks < 2; ++ks)
                af[f][ks] = ldsfrag(Ah, 64 + f * 16 + l15, ks * 4 + g4);
        if (doB) stage_half(BgN2, K, stB, tid);
        BARRIER();
        __builtin_amdgcn_s_setprio(1);
        #pragma unroll
        for (int f = 0; f < 4; ++f)
            #pragma unroll
            for (int fn = 0; fn < 2; ++fn)
                #pragma unroll
                for (int ks = 0; ks < 2; ++ks)
                    acc[4 + f][fn] = __builtin_amdgcn_mfma_f32_16x16x32_bf16(
                        af[f][ks], b0[fn][ks], acc[4 + f][fn], 0, 0, 0);
        __builtin_amdgcn_s_setprio(0);
        BARRIER();

        // ---------- phase 3: (mh1, nh1) ----------
        if (doB) stage_half(BgN2 + (size_t)128 * K, K, stB + 8192, tid);
        BARRIER();
        __builtin_amdgcn_s_setprio(1);
        #pragma unroll
        for (int f = 0; f < 4; ++f)
            #pragma unroll
            for (int fn = 0; fn < 2; ++fn)
                #pragma unroll
                for (int ks = 0; ks < 2; ++ks)
                    acc[4 + f][2 + fn] = __builtin_amdgcn_mfma_f32_16x16x32_bf16(
                        af[f][ks], b1[fn][ks], acc[4 + f][2 + fn], 0, 0, 0);
        __builtin_amdgcn_s_setprio(0);
        if (doB) { WAITVM(4); } else { WAITVM(0); }
        BARRIER();
    }

    // ---- epilogue: direct bf16 C writes (m89 layout) ----
    const size_t r0 = (size_t)tm * 256 + wr * 128 + g4 * 4;
    const int    c0 = tn * 256 + wc * 64 + l15;
    #pragma unroll
    for (int mf = 0; mf < 8; ++mf)
        #pragma unroll
        for (int nf = 0; nf < 4; ++nf)
            #pragma unroll
            for (int j = 0; j < 4; ++j)
                C[(r0 + mf * 16 + j) * N + c0 + nf * 16] = f2bf(acc[mf][nf][j]);
}

// ---------------------------------------------------------------------------
// GEMM2 kernel (128x128, gload_lds) — unchanged from r2
// ---------------------------------------------------------------------------
template<bool OUT_F32>
__global__ __launch_bounds__(256)
void gemm_bt(const short* __restrict__ A, const short* __restrict__ B,
             void* __restrict__ Cp, int M, int N, int K) {
    __shared__ short As[128 * 32];
    __shared__ short Bs[128 * 32];

    const int tid  = threadIdx.x;
    const int lane = tid & 63;
    const int wid  = tid >> 6;
    const int wr   = wid >> 1;
    const int wc   = wid & 1;
    const int brow = blockIdx.y * 128;
    const int bcol = blockIdx.x * 128;

    const int l15 = lane & 15;
    const int grp = lane >> 4;
    const int sr = lane >> 2;
    const int sc = (lane & 3) ^ ((sr & 1) << 1);

    f32x4 acc[4][4] = {};

    for (int k0 = 0; k0 < K; k0 += 32) {
        #pragma unroll
        for (int it = 0; it < 2; it++) {
            int cb = wid + it * 4;
            int r  = cb * 16 + sr;
            gload16(A + (size_t)(brow + r) * K + k0 + sc * 8, &As[cb * 512]);
            gload16(B + (size_t)(bcol + r) * K + k0 + sc * 8, &Bs[cb * 512]);
        }
        __syncthreads();

        bf16x8 a[4], b[4];
        #pragma unroll
        for (int m = 0; m < 4; m++) {
            int rA = wr * 64 + m * 16 + l15;
            int ch = grp ^ ((rA & 1) << 1);
            a[m] = *(const bf16x8*)(&As[rA * 32 + ch * 8]);
        }
        #pragma unroll
        for (int n = 0; n < 4; n++) {
            int rB = wc * 64 + n * 16 + l15;
            int ch = grp ^ ((rB & 1) << 1);
            b[n] = *(const bf16x8*)(&Bs[rB * 32 + ch * 8]);
        }
        #pragma unroll
        for (int m = 0; m < 4; m++)
            #pragma unroll
            for (int n = 0; n < 4; n++)
                acc[m][n] = __builtin_amdgcn_mfma_f32_16x16x32_bf16(a[m], b[n], acc[m][n], 0, 0, 0);
        __syncthreads();
    }

    const int r0 = brow + wr * 64 + (lane >> 4) * 4;
    const int c0 = bcol + wc * 64 + l15;
    if (OUT_F32) {
        float* C = (float*)Cp;
        #pragma unroll
        for (int m = 0; m < 4; m++)
            #pragma unroll
            for (int n = 0; n < 4; n++)
                #pragma unroll
                for (int j = 0; j < 4; j++)
                    C[(size_t)(r0 + m * 16 + j) * N + c0 + n * 16] = acc[m][n][j];
    } else {
        short* C = (short*)Cp;
        #pragma unroll
        for (int m = 0; m < 4; m++)
            #pragma unroll
            for (int n = 0; n < 4; n++)
                #pragma unroll
                for (int j = 0; j < 4; j++)
                    C[(size_t)(r0 + m * 16 + j) * N + c0 + n * 16] = f2bf(acc[m][n][j]);
    }
}

// ---------------------------------------------------------------------------
// Flash attention v4 (unchanged from r3): swapped-QK^T 32x32, exp2 softmax,
// permlane pack, defer-max, double-buffered prefetch, setprio.
// ---------------------------------------------------------------------------
__global__ __launch_bounds__(512, 4)
void attn_fwd(const short* __restrict__ qkv, short* __restrict__ Y) {
    __shared__ __align__(16) char smem[34816];
    short* const KsB0 = (short*)smem;
    short* const VtB0 = (short*)smem + 4096;
    short* const KsB1 = (short*)smem + 8192;
    short* const VtB1 = (short*)smem + 12288;

    const int tid  = threadIdx.x;
    const int lane = tid & 63;
    const int w    = tid >> 6;
    const int q    = lane & 31;
    const int hf   = lane >> 5;

    const int b  = blockIdx.x >> 4;
    const int h  = blockIdx.x & 15;
    const int qt = (gridDim.y - 1) - blockIdx.y;
    const int g  = w >> 1;
    const int lq = (w & 1) * 32 + q;
    const size_t RS = 6144;
    const int bT = b * 1024;

    bf16x8 qf[4];
    {
        const short* qp = qkv + (size_t)(bT + qt * 64 + lq) * RS + g * 1024 + h * 64 + 8 * hf;
        #pragma unroll
        for (int ks2 = 0; ks2 < 4; ks2++)
            qf[ks2] = *(const bf16x8*)(qp + 16 * ks2);
    }

    f32x16 ot[2] = {};
    float m_run = -3e38f, lsum = 0.f;

    const int kvS   = tid >> 3;
    const int klog  = (tid & 7) ^ (kvS & 7);
    const int d2    = tid >> 4;
    const int ch4   = tid & 15;
    const int vd0   = d2 * 2;
    const int vp0   = (ch4 >> 1) ^ (vd0 & 7);
    const int vp1   = (ch4 >> 1) ^ ((vd0 + 1) & 7);

    const short* const kvtile = qkv + (size_t)bT * RS + h * 64;

    {
        const short* vp = kvtile + (size_t)(ch4 * 4) * RS + 5120 + vd0;
        unsigned v0 = *(const unsigned*)(vp);
        unsigned v1 = *(const unsigned*)(vp + RS);
        unsigned v2 = *(const unsigned*)(vp + 2 * RS);
        unsigned v3 = *(const unsigned*)(vp + 3 * RS);
        gload16(kvtile + (size_t)kvS * RS + 4096 + klog * 8, KsB0 + w * 512);
        uint2 lo, hi2;
        lo.x  = __builtin_amdgcn_perm(v1, v0, 0x05040100u);
        lo.y  = __builtin_amdgcn_perm(v3, v2, 0x05040100u);
        hi2.x = __builtin_amdgcn_perm(v1, v0, 0x07060302u);
        hi2.y = __builtin_amdgcn_perm(v3, v2, 0x07060302u);
        char* vb = (char*)VtB0;
        *(uint2*)(vb + vd0 * 128 + vp0 * 16 + (ch4 & 1) * 8)       = lo;
        *(uint2*)(vb + (vd0 + 1) * 128 + vp1 * 16 + (ch4 & 1) * 8) = hi2;
    }
    __syncthreads();

    for (int kvt = 0; kvt <= qt; kvt++) {
        short* const Ksc = (kvt & 1) ? KsB1 : KsB0;
        short* const Vtc = (kvt & 1) ? VtB1 : VtB0;
        short* const Ksn = (kvt & 1) ? KsB0 : KsB1;
        short* const Vtn = (kvt & 1) ? VtB0 : VtB1;
        const bool pf = (kvt < qt);

        unsigned v0, v1, v2, v3;
        if (pf) {
            const short* vp = kvtile + (size_t)((kvt + 1) * 64 + ch4 * 4) * RS + 5120 + vd0;
            v0 = *(const unsigned*)(vp);
            v1 = *(const unsigned*)(vp + RS);
            v2 = *(const unsigned*)(vp + 2 * RS);
            v3 = *(const unsigned*)(vp + 3 * RS);
            gload16(kvtile + (size_t)((kvt + 1) * 64 + kvS) * RS + 4096 + klog * 8,
                    Ksn + w * 512);
        }

        f32x16 stt[2] = {};
        __builtin_amdgcn_s_setprio(1);
        #pragma unroll
        for (int sti = 0; sti < 2; sti++) {
            const int kvr = sti * 32 + q;
            #pragma unroll
            for (int ks2 = 0; ks2 < 4; ks2++) {
                const int phys = (2 * ks2 + hf) ^ (kvr & 7);
                bf16x8 kf = *(const bf16x8*)(Ksc + kvr * 64 + phys * 8);
                stt[sti] = __builtin_amdgcn_mfma_f32_32x32x16_bf16(kf, qf[ks2], stt[sti], 0, 0, 0);
            }
        }
        __builtin_amdgcn_s_setprio(0);

        if (kvt == qt) {
            #pragma unroll
            for (int sti = 0; sti < 2; sti++)
                #pragma unroll
                for (int r = 0; r < 16; r++) {
                    int kvl = sti * 32 + (r & 3) + 8 * (r >> 2) + 4 * hf;
                    if (kvl > lq) stt[sti][r] = -3e38f;
                }
        }

        float pm[4] = { -3e38f, -3e38f, -3e38f, -3e38f };
        #pragma unroll
        for (int r = 0; r < 16; r++)
            pm[r & 3] = fmaxf(pm[r & 3], fmaxf(stt[0][r], stt[1][r]));
        float mx = fmaxf(fmaxf(pm[0], pm[1]), fmaxf(pm[2], pm[3]));
        mx = fmaxf(mx, __shfl_xor(mx, 32));

        if (!__all(mx - m_run <= 8.0f)) {
            const float mn = fmaxf(m_run, mx);
            const float alpha = __builtin_amdgcn_exp2f(m_run - mn);
            m_run = mn;
            lsum *= alpha;
            ot[0] *= alpha;
            ot[1] *= alpha;
        }

        float sp[4] = { 0.f, 0.f, 0.f, 0.f };
        #pragma unroll
        for (int sti = 0; sti < 2; sti++)
            #pragma unroll
            for (int r = 0; r < 16; r++) {
                float e = __builtin_amdgcn_exp2f(stt[sti][r] - m_run);
                stt[sti][r] = e;
                sp[r & 3] += e;
            }
        float sum = (sp[0] + sp[1]) + (sp[2] + sp[3]);
        sum += __shfl_xor(sum, 32);
        lsum += sum;

        if (pf) {
            uint2 lo, hi2;
            lo.x  = __builtin_amdgcn_perm(v1, v0, 0x05040100u);
            lo.y  = __builtin_amdgcn_perm(v3, v2, 0x05040100u);
            hi2.x = __builtin_amdgcn_perm(v1, v0, 0x07060302u);
            hi2.y = __builtin_amdgcn_perm(v3, v2, 0x07060302u);
            char* vb = (char*)Vtn;
            *(uint2*)(vb + vd0 * 128 + vp0 * 16 + (ch4 & 1) * 8)       = lo;
            *(uint2*)(vb + (vd0 + 1) * 128 + vp1 * 16 + (ch4 & 1) * 8) = hi2;
        }

        bf16x8 pf4[4];
        #pragma unroll
        for (int ks = 0; ks < 4; ks++) {
            const int sti = ks >> 1, base = 8 * (ks & 1);
            unsigned X0 = pk2bf(stt[sti][base + 0], stt[sti][base + 1]);
            unsigned X1 = pk2bf(stt[sti][base + 2], stt[sti][base + 3]);
            unsigned Y0 = pk2bf(stt[sti][base + 4], stt[sti][base + 5]);
            unsigned Y1 = pk2bf(stt[sti][base + 6], stt[sti][base + 7]);
            asm("v_permlane32_swap_b32 %0, %1" : "+v"(X0), "+v"(Y0));
            asm("v_permlane32_swap_b32 %0, %1" : "+v"(X1), "+v"(Y1));
            unsigned t[4] = { X0, X1, Y0, Y1 };
            pf4[ks] = *(bf16x8*)t;
        }

        __builtin_amdgcn_s_setprio(1);
        #pragma unroll
        for (int dsub = 0; dsub < 2; dsub++) {
            const int dr = dsub * 32 + q;
            #pragma unroll
            for (int ks = 0; ks < 4; ks++) {
                const int phys = (2 * ks + hf) ^ (dr & 7);
                bf16x8 vf = *(const bf16x8*)(Vtc + dr * 64 + phys * 8);
                ot[dsub] = __builtin_amdgcn_mfma_f32_32x32x16_bf16(vf, pf4[ks], ot[dsub], 0, 0, 0);
            }
        }
        __builtin_amdgcn_s_setprio(0);

        __syncthreads();
    }

    unsigned* obuf = (unsigned*)smem;
    const float inv = 1.0f / lsum;
    const int SQ = g * 64 + lq;
    #pragma unroll
    for (int dsub = 0; dsub < 2; dsub++)
        #pragma unroll
        for (int r = 0; r < 16; r += 2) {
            int d = dsub * 32 + (r & 3) + 8 * (r >> 2) + 4 * hf;
            unsigned pk = ((unsigned)(unsigned short)f2bf(ot[dsub][r] * inv)) |
                          (((unsigned)(unsigned short)f2bf(ot[dsub][r + 1] * inv)) << 16);
            obuf[SQ * 34 + (d >> 1)] = pk;
        }
    __syncthreads();
    {
        const int SQ2 = tid >> 1, seg = tid & 1;
        const int g2 = SQ2 >> 6, lq2 = SQ2 & 63;
        const size_t row = (size_t)(bT + qt * 64 + lq2);
        const unsigned* src = obuf + SQ2 * 34 + seg * 16;
        unsigned* dst = (unsigned*)(Y + row * 4096 + g2 * 1024 + h * 64 + seg * 32);
        #pragma unroll
        for (int k = 0; k < 4; k++) {
            uint2 u0 = *(const uint2*)(src + 4 * k);
            uint2 u1 = *(const uint2*)(src + 4 * k + 2);
            uint4 t; t.x = u0.x; t.y = u0.y; t.z = u1.x; t.w = u1.y;
            *(uint4*)(dst + 4 * k) = t;
        }
    }
}

// ---------------------------------------------------------------------------
extern "C" void kernel_launch(void* const* d_in, const int* in_sizes, int n_in,
                              void* d_out, int out_size, void* d_ws, size_t ws_size,
                              hipStream_t stream) {
    const float* x  = (const float*)d_in[0];   // [8192,1024]
    const float* Wa = (const float*)d_in[1];   // [6144,1024]
    const float* Wp = (const float*)d_in[2];   // [1024,4096]
    float* out = (float*)d_out;

    short* qkv = (short*)d_ws;                        // 50331648 shorts
    short* Yb  = qkv + (size_t)8192 * 6144;           // 33554432 shorts
    short* xb  = Yb;                                  // pre-attn reuse of Yb
    short* Wab = Yb + (size_t)8192 * 1024;            // pre-attn reuse of Yb
    short* Wpb = qkv;                                 // post-attn reuse of qkv

    const float QS = 0.18033688011112042f;            // 0.125 * log2(e)
    dim3 blk(256);
    cvt_bf16<<<dim3(8192 * 1024 / 8 / 256), blk, 0, stream>>>(x, xb, 8192 * 1024 / 8, 1.0f);
    cvt_bf16<<<dim3(4096 * 1024 / 8 / 256), blk, 0, stream>>>(Wa, Wab, 4096 * 1024 / 8, QS);
    cvt_bf16<<<dim3(2048 * 1024 / 8 / 256), blk, 0, stream>>>(
        Wa + (size_t)4096 * 1024, Wab + (size_t)4096 * 1024, 2048 * 1024 / 8, 1.0f);
    // qkv = x @ W_attn^T   (M=8192, N=6144, K=1024): 32 x 24 = 768 wgs
    gemm8_bt<<<dim3(768), dim3(512), 0, stream>>>(xb, Wab, qkv, 8192, 6144, 1024, 24);
    // flash attention -> Y   (128 combos x 16 q-tiles, 512 thr)
    attn_fwd<<<dim3(128, 16), dim3(512), 0, stream>>>(qkv, Yb);
    // out = Y @ W_proj^T   (M=8192, N=1024, K=4096)
    cvt_bf16<<<dim3(1024 * 4096 / 8 / 256), blk, 0, stream>>>(Wp, Wpb, 1024 * 4096 / 8, 1.0f);
    gemm_bt<true><<<dim3(8, 64), blk, 0, stream>>>(Yb, Wpb, (void*)out, 8192, 1024, 4096);
}

// Round 6
// 339.151 us; speedup vs baseline: 2.0898x; 1.0934x over previous
//
#include <hip/hip_runtime.h>

// ---------------------------------------------------------------------------
// CausalSelfAttention (GQA, 4 query sets sharing K/V)
//   B=8, T=1024, C=1024, H=16, hd=64, G=4
// Pipeline: cvt_all(x,Wa)->bf16, GEMM1 = 256^2 8-phase, attn v4,
// cvt(Wp), GEMM2 = 256x128 2-phase (same template, counted vmcnt).
// ws layout (shorts):
//   qkv  [8192*6144] @ 0          (Wpb reuses first 4.2M after attn)
//   Yb   [8192*4096] @ 50331648   (xb, Wab live here before attn)
// ---------------------------------------------------------------------------

#define DEVI __device__ __forceinline__

typedef __attribute__((ext_vector_type(4)))  float f32x4;
typedef __attribute__((ext_vector_type(16))) float f32x16;
typedef __attribute__((ext_vector_type(8)))  short bf16x8;

static DEVI short f2bf(float f) {
    union { float f; unsigned int i; } c; c.f = f;
    unsigned int i = c.i;
    unsigned int r = i + 0x7FFFu + ((i >> 16) & 1u);   // RNE
    return (short)(r >> 16);
}

static DEVI unsigned pk2bf(float a, float b) {
    return __builtin_amdgcn_perm(__float_as_uint(b), __float_as_uint(a), 0x07060302u);
}

static DEVI void gload16(const void* g, void* l) {
    __builtin_amdgcn_global_load_lds(
        (const __attribute__((address_space(1))) unsigned int*)g,
        (__attribute__((address_space(3))) unsigned int*)l,
        16, 0, 0);
}

#define BARRIER() do { __builtin_amdgcn_s_barrier(); \
                       __builtin_amdgcn_sched_barrier(0); } while (0)
#define WAITVM(n) do { asm volatile("s_waitcnt vmcnt(%0)" :: "i"(n) : "memory"); \
                       __builtin_amdgcn_sched_barrier(0); } while (0)

// ---------------------------------------------------------------------------
// fused fp32 -> bf16 convert for x (scale 1) and W_attn (Q rows scaled)
//   dst is contiguous: [x 8.39M shorts][Wa 6.29M shorts]
// ---------------------------------------------------------------------------
__global__ __launch_bounds__(256)
void cvt_all(const float* __restrict__ x, const float* __restrict__ Wa,
             short* __restrict__ dst, float qs) {
    const int i = blockIdx.x * 256 + threadIdx.x;       // 0..1835007
    const int X8 = 1048576, WQ8 = 524288;
    const float* src;
    float scale = 1.0f;
    if (i < X8) {
        src = x + (size_t)i * 8;
    } else {
        int j = i - X8;
        src = Wa + (size_t)j * 8;
        if (j < WQ8) scale = qs;
    }
    const float4* p = (const float4*)src;
    float4 v0 = p[0], v1 = p[1];
    short r[8] = { f2bf(v0.x * scale), f2bf(v0.y * scale),
                   f2bf(v0.z * scale), f2bf(v0.w * scale),
                   f2bf(v1.x * scale), f2bf(v1.y * scale),
                   f2bf(v1.z * scale), f2bf(v1.w * scale) };
    *(uint4*)(dst + (size_t)i * 8) = *(uint4*)r;
}

__global__ __launch_bounds__(256)
void cvt_bf16(const float* __restrict__ in, short* __restrict__ out, int n8,
              float scale) {
    int i = blockIdx.x * 256 + threadIdx.x;
    if (i >= n8) return;
    const float4* p = (const float4*)in + (size_t)i * 2;
    float4 v0 = p[0], v1 = p[1];
    short r[8] = { f2bf(v0.x * scale), f2bf(v0.y * scale),
                   f2bf(v0.z * scale), f2bf(v0.w * scale),
                   f2bf(v1.x * scale), f2bf(v1.y * scale),
                   f2bf(v1.z * scale), f2bf(v1.w * scale) };
    *(uint4*)(out + (size_t)i * 8) = *(uint4*)r;
}

// ---------------------------------------------------------------------------
// shared staging / frag-read helpers (st-swizzle, both-sides involution)
// ---------------------------------------------------------------------------
static DEVI void stage_half(const short* __restrict__ G, int ldg,
                            short* ldsHalf, int tid) {
    #pragma unroll
    for (int i = 0; i < 2; ++i) {
        int c = tid + (i << 9);                       // chunk id
        int row = c >> 3;
        int k8 = (c & 7) ^ (((row >> 2) & 1) << 1);   // inverse swizzle on src
        gload16(G + (size_t)row * ldg + k8 * 8, ldsHalf + ((c >> 6) << 9));
    }
}

static DEVI bf16x8 ldsfrag(const short* half, int lr, int k8r) {
    int off = lr * 64 + ((k8r * 8) ^ (((lr >> 2) & 1) << 4));
    return *(const bf16x8*)(half + off);
}

// ---------------------------------------------------------------------------
// GEMM1: 256x256 tile, BK=64, 8-phase schedule (unchanged from r4)
// ---------------------------------------------------------------------------
__global__ __launch_bounds__(512)
void gemm8_bt(const short* __restrict__ A, const short* __restrict__ B,
              short* __restrict__ C, int M, int N, int K, int nwgN) {
    __shared__ short lds[65536];                      // 128 KB
    short* const ldsA = lds;                          // [2][2][8192]
    short* const ldsB = lds + 32768;

    const int tid  = threadIdx.x;
    const int lane = tid & 63;
    const int w    = tid >> 6;
    const int wr   = w >> 2;
    const int wc   = w & 3;
    const int l15  = lane & 15;
    const int g4   = lane >> 4;

    const int nwg = gridDim.x;
    const int wg  = blockIdx.x;
    const int swz = (wg & 7) * (nwg >> 3) + (wg >> 3);
    const int tm  = swz / nwgN, tn = swz % nwgN;

    const short* Ag = A + (size_t)tm * 256 * K;
    const short* Bg = B + (size_t)tn * 256 * K;
    const int NT = K >> 6;

    f32x4 acc[8][4] = {};

    stage_half(Ag,                      K, ldsA,               tid);
    stage_half(Ag + (size_t)128 * K,    K, ldsA + 8192,        tid);
    stage_half(Bg,                      K, ldsB,               tid);
    stage_half(Bg + (size_t)128 * K,    K, ldsB + 8192,        tid);
    stage_half(Bg + 64,                 K, ldsB + 16384,       tid);
    stage_half(Bg + (size_t)128 * K + 64, K, ldsB + 16384 + 8192, tid);
    WAITVM(4);
    BARRIER();

    for (int u = 0; u < NT; ++u) {
        const int buf = u & 1;
        const short* Ah = ldsA + buf * 16384 + wr * 8192;
        const short* Bh = ldsB + buf * 16384 + (wc >> 1) * 8192;
        const int lrB = (wc & 1) * 64;
        short* stA = ldsA + (buf ^ 1) * 16384;
        short* stB = ldsB + buf * 16384;
        const short* AgN  = Ag + (size_t)(u + 1) * 64;
        const short* BgN2 = Bg + (size_t)(u + 2) * 64;
        const bool doA = (u + 1 < NT), doB = (u + 2 < NT);

        bf16x8 af[4][2], b0[2][2], b1[2][2];

        // phase 0: (mh0, nh0)
        #pragma unroll
        for (int f = 0; f < 4; ++f)
            #pragma unroll
            for (int ks = 0; ks < 2; ++ks)
                af[f][ks] = ldsfrag(Ah, f * 16 + l15, ks * 4 + g4);
        #pragma unroll
        for (int fn = 0; fn < 2; ++fn)
            #pragma unroll
            for (int ks = 0; ks < 2; ++ks)
                b0[fn][ks] = ldsfrag(Bh, lrB + fn * 16 + l15, ks * 4 + g4);
        if (doA) stage_half(AgN, K, stA, tid);
        BARRIER();
        __builtin_amdgcn_s_setprio(1);
        #pragma unroll
        for (int f = 0; f < 4; ++f)
            #pragma unroll
            for (int fn = 0; fn < 2; ++fn)
                #pragma unroll
                for (int ks = 0; ks < 2; ++ks)
                    acc[f][fn] = __builtin_amdgcn_mfma_f32_16x16x32_bf16(
                        af[f][ks], b0[fn][ks], acc[f][fn], 0, 0, 0);
        __builtin_amdgcn_s_setprio(0);
        BARRIER();

        // phase 1: (mh0, nh1)
        #pragma unroll
        for (int fn = 0; fn < 2; ++fn)
            #pragma unroll
            for (int ks = 0; ks < 2; ++ks)
                b1[fn][ks] = ldsfrag(Bh, lrB + 32 + fn * 16 + l15, ks * 4 + g4);
        if (doA) stage_half(AgN + (size_t)128 * K, K, stA + 8192, tid);
        BARRIER();
        __builtin_amdgcn_s_setprio(1);
        #pragma unroll
        for (int f = 0; f < 4; ++f)
            #pragma unroll
            for (int fn = 0; fn < 2; ++fn)
                #pragma unroll
                for (int ks = 0; ks < 2; ++ks)
                    acc[f][2 + fn] = __builtin_amdgcn_mfma_f32_16x16x32_bf16(
                        af[f][ks], b1[fn][ks], acc[f][2 + fn], 0, 0, 0);
        __builtin_amdgcn_s_setprio(0);
        BARRIER();

        // phase 2: (mh1, nh0)
        #pragma unroll
        for (int f = 0; f < 4; ++f)
            #pragma unroll
            for (int ks = 0; ks < 2; ++ks)
                af[f][ks] = ldsfrag(Ah, 64 + f * 16 + l15, ks * 4 + g4);
        if (doB) stage_half(BgN2, K, stB, tid);
        BARRIER();
        __builtin_amdgcn_s_setprio(1);
        #pragma unroll
        for (int f = 0; f < 4; ++f)
            #pragma unroll
            for (int fn = 0; fn < 2; ++fn)
                #pragma unroll
                for (int ks = 0; ks < 2; ++ks)
                    acc[4 + f][fn] = __builtin_amdgcn_mfma_f32_16x16x32_bf16(
                        af[f][ks], b0[fn][ks], acc[4 + f][fn], 0, 0, 0);
        __builtin_amdgcn_s_setprio(0);
        BARRIER();

        // phase 3: (mh1, nh1)
        if (doB) stage_half(BgN2 + (size_t)128 * K, K, stB + 8192, tid);
        BARRIER();
        __builtin_amdgcn_s_setprio(1);
        #pragma unroll
        for (int f = 0; f < 4; ++f)
            #pragma unroll
            for (int fn = 0; fn < 2; ++fn)
                #pragma unroll
                for (int ks = 0; ks < 2; ++ks)
                    acc[4 + f][2 + fn] = __builtin_amdgcn_mfma_f32_16x16x32_bf16(
                        af[f][ks], b1[fn][ks], acc[4 + f][2 + fn], 0, 0, 0);
        __builtin_amdgcn_s_setprio(0);
        if (doB) { WAITVM(4); } else { WAITVM(0); }
        BARRIER();
    }

    const size_t r0 = (size_t)tm * 256 + wr * 128 + g4 * 4;
    const int    c0 = tn * 256 + wc * 64 + l15;
    #pragma unroll
    for (int mf = 0; mf < 8; ++mf)
        #pragma unroll
        for (int nf = 0; nf < 4; ++nf)
            #pragma unroll
            for (int j = 0; j < 4; ++j)
                C[(r0 + mf * 16 + j) * N + c0 + nf * 16] = f2bf(acc[mf][nf][j]);
}

// ---------------------------------------------------------------------------
// GEMM2: 256x128 tile, BK=64, 2-phase schedule, fp32 output.
//   8 waves (2M x 4N), per-wave 128x32 = 8x2 frags.
//   LDS 96KB: A[2buf][2half][128][64] (64KB) + B[2buf][128][64] (32KB).
//   Staging: A-h0(u+1)@ph0 -> bufA^1; A-h1(u+1)+B(u+2)@ph1 (B into bufB[u&1],
//   dead since ph0's closing barrier). Tile-end vmcnt(2) keeps exactly
//   B(u+2)'s 2 loads in flight (counted, never 0 mid-loop).
// ---------------------------------------------------------------------------
__global__ __launch_bounds__(512)
void gemm8_bt2(const short* __restrict__ A, const short* __restrict__ B,
               float* __restrict__ C, int M, int N, int K) {
    __shared__ short lds[49152];                      // 96 KB
    short* const ldsA = lds;                          // [2][2][8192]
    short* const ldsB = lds + 32768;                  // [2][8192]

    const int tid  = threadIdx.x;
    const int lane = tid & 63;
    const int w    = tid >> 6;
    const int wr   = w >> 2;                          // 0..1 (M half)
    const int wc   = w & 3;                           // 0..3 (32-col block)
    const int l15  = lane & 15;
    const int g4   = lane >> 4;

    const int nwg = gridDim.x;                        // 256
    const int wg  = blockIdx.x;
    const int swz = (wg & 7) * (nwg >> 3) + (wg >> 3);
    const int tm  = swz >> 3, tn = swz & 7;           // nwgN = 8

    const short* Ag = A + (size_t)tm * 256 * K;
    const short* Bg = B + (size_t)tn * 128 * K;
    const int NT = K >> 6;

    f32x4 acc[8][2] = {};

    // prologue: A(0) h0,h1; B(0); B(1)
    stage_half(Ag,                   K, ldsA,        tid);
    stage_half(Ag + (size_t)128 * K, K, ldsA + 8192, tid);
    stage_half(Bg,                   K, ldsB,        tid);
    stage_half(Bg + 64,              K, ldsB + 8192, tid);
    WAITVM(2);                                        // keep B(1) in flight
    BARRIER();

    for (int u = 0; u < NT; ++u) {
        const int buf = u & 1;
        const short* Ah = ldsA + buf * 16384 + wr * 8192;
        const short* Bb = ldsB + buf * 8192;
        short* stA = ldsA + (buf ^ 1) * 16384;        // tile u+1
        short* stB = ldsB + buf * 8192;               // tile u+2 (same parity)
        const short* AgN  = Ag + (size_t)(u + 1) * 64;
        const short* BgN2 = Bg + (size_t)(u + 2) * 64;
        const bool doA = (u + 1 < NT), doB = (u + 2 < NT);

        bf16x8 af[4][2], b[2][2];

        // ---------- phase 0: mh0 ----------
        #pragma unroll
        for (int f = 0; f < 4; ++f)
            #pragma unroll
            for (int ks = 0; ks < 2; ++ks)
                af[f][ks] = ldsfrag(Ah, f * 16 + l15, ks * 4 + g4);
        #pragma unroll
        for (int fn = 0; fn < 2; ++fn)
            #pragma unroll
            for (int ks = 0; ks < 2; ++ks)
                b[fn][ks] = ldsfrag(Bb, wc * 32 + fn * 16 + l15, ks * 4 + g4);
        if (doA) stage_half(AgN, K, stA, tid);
        BARRIER();
        __builtin_amdgcn_s_setprio(1);
        #pragma unroll
        for (int f = 0; f < 4; ++f)
            #pragma unroll
            for (int fn = 0; fn < 2; ++fn)
                #pragma unroll
                for (int ks = 0; ks < 2; ++ks)
                    acc[f][fn] = __builtin_amdgcn_mfma_f32_16x16x32_bf16(
                        af[f][ks], b[fn][ks], acc[f][fn], 0, 0, 0);
        __builtin_amdgcn_s_setprio(0);
        BARRIER();

        // ---------- phase 1: mh1 ----------
        #pragma unroll
        for (int f = 0; f < 4; ++f)
            #pragma unroll
            for (int ks = 0; ks < 2; ++ks)
                af[f][ks] = ldsfrag(Ah, 64 + f * 16 + l15, ks * 4 + g4);
        if (doA) stage_half(AgN + (size_t)128 * K, K, stA + 8192, tid);
        if (doB) stage_half(BgN2, K, stB, tid);       // youngest 2 loads
        BARRIER();
        __builtin_amdgcn_s_setprio(1);
        #pragma unroll
        for (int f = 0; f < 4; ++f)
            #pragma unroll
            for (int fn = 0; fn < 2; ++fn)
                #pragma unroll
                for (int ks = 0; ks < 2; ++ks)
                    acc[4 + f][fn] = __builtin_amdgcn_mfma_f32_16x16x32_bf16(
                        af[f][ks], b[fn][ks], acc[4 + f][fn], 0, 0, 0);
        __builtin_amdgcn_s_setprio(0);
        if (doB) { WAITVM(2); } else { WAITVM(0); }
        BARRIER();
    }

    // epilogue: fp32 C (m89 layout)
    const size_t r0 = (size_t)tm * 256 + wr * 128 + g4 * 4;
    const int    c0 = tn * 128 + wc * 32 + l15;
    #pragma unroll
    for (int mf = 0; mf < 8; ++mf)
        #pragma unroll
        for (int nf = 0; nf < 2; ++nf)
            #pragma unroll
            for (int j = 0; j < 4; ++j)
                C[(r0 + mf * 16 + j) * N + c0 + nf * 16] = acc[mf][nf][j];
}

// ---------------------------------------------------------------------------
// Flash attention v4 (unchanged from r4)
// ---------------------------------------------------------------------------
__global__ __launch_bounds__(512, 4)
void attn_fwd(const short* __restrict__ qkv, short* __restrict__ Y) {
    __shared__ __align__(16) char smem[34816];
    short* const KsB0 = (short*)smem;
    short* const VtB0 = (short*)smem + 4096;
    short* const KsB1 = (short*)smem + 8192;
    short* const VtB1 = (short*)smem + 12288;

    const int tid  = threadIdx.x;
    const int lane = tid & 63;
    const int w    = tid >> 6;
    const int q    = lane & 31;
    const int hf   = lane >> 5;

    const int b  = blockIdx.x >> 4;
    const int h  = blockIdx.x & 15;
    const int qt = (gridDim.y - 1) - blockIdx.y;
    const int g  = w >> 1;
    const int lq = (w & 1) * 32 + q;
    const size_t RS = 6144;
    const int bT = b * 1024;

    bf16x8 qf[4];
    {
        const short* qp = qkv + (size_t)(bT + qt * 64 + lq) * RS + g * 1024 + h * 64 + 8 * hf;
        #pragma unroll
        for (int ks2 = 0; ks2 < 4; ks2++)
            qf[ks2] = *(const bf16x8*)(qp + 16 * ks2);
    }

    f32x16 ot[2] = {};
    float m_run = -3e38f, lsum = 0.f;

    const int kvS   = tid >> 3;
    const int klog  = (tid & 7) ^ (kvS & 7);
    const int d2    = tid >> 4;
    const int ch4   = tid & 15;
    const int vd0   = d2 * 2;
    const int vp0   = (ch4 >> 1) ^ (vd0 & 7);
    const int vp1   = (ch4 >> 1) ^ ((vd0 + 1) & 7);

    const short* const kvtile = qkv + (size_t)bT * RS + h * 64;

    {
        const short* vp = kvtile + (size_t)(ch4 * 4) * RS + 5120 + vd0;
        unsigned v0 = *(const unsigned*)(vp);
        unsigned v1 = *(const unsigned*)(vp + RS);
        unsigned v2 = *(const unsigned*)(vp + 2 * RS);
        unsigned v3 = *(const unsigned*)(vp + 3 * RS);
        gload16(kvtile + (size_t)kvS * RS + 4096 + klog * 8, KsB0 + w * 512);
        uint2 lo, hi2;
        lo.x  = __builtin_amdgcn_perm(v1, v0, 0x05040100u);
        lo.y  = __builtin_amdgcn_perm(v3, v2, 0x05040100u);
        hi2.x = __builtin_amdgcn_perm(v1, v0, 0x07060302u);
        hi2.y = __builtin_amdgcn_perm(v3, v2, 0x07060302u);
        char* vb = (char*)VtB0;
        *(uint2*)(vb + vd0 * 128 + vp0 * 16 + (ch4 & 1) * 8)       = lo;
        *(uint2*)(vb + (vd0 + 1) * 128 + vp1 * 16 + (ch4 & 1) * 8) = hi2;
    }
    __syncthreads();

    for (int kvt = 0; kvt <= qt; kvt++) {
        short* const Ksc = (kvt & 1) ? KsB1 : KsB0;
        short* const Vtc = (kvt & 1) ? VtB1 : VtB0;
        short* const Ksn = (kvt & 1) ? KsB0 : KsB1;
        short* const Vtn = (kvt & 1) ? VtB0 : VtB1;
        const bool pf = (kvt < qt);

        unsigned v0, v1, v2, v3;
        if (pf) {
            const short* vp = kvtile + (size_t)((kvt + 1) * 64 + ch4 * 4) * RS + 5120 + vd0;
            v0 = *(const unsigned*)(vp);
            v1 = *(const unsigned*)(vp + RS);
            v2 = *(const unsigned*)(vp + 2 * RS);
            v3 = *(const unsigned*)(vp + 3 * RS);
            gload16(kvtile + (size_t)((kvt + 1) * 64 + kvS) * RS + 4096 + klog * 8,
                    Ksn + w * 512);
        }

        f32x16 stt[2] = {};
        __builtin_amdgcn_s_setprio(1);
        #pragma unroll
        for (int sti = 0; sti < 2; sti++) {
            const int kvr = sti * 32 + q;
            #pragma unroll
            for (int ks2 = 0; ks2 < 4; ks2++) {
                const int phys = (2 * ks2 + hf) ^ (kvr & 7);
                bf16x8 kf = *(const bf16x8*)(Ksc + kvr * 64 + phys * 8);
                stt[sti] = __builtin_amdgcn_mfma_f32_32x32x16_bf16(kf, qf[ks2], stt[sti], 0, 0, 0);
            }
        }
        __builtin_amdgcn_s_setprio(0);

        if (kvt == qt) {
            #pragma unroll
            for (int sti = 0; sti < 2; sti++)
                #pragma unroll
                for (int r = 0; r < 16; r++) {
                    int kvl = sti * 32 + (r & 3) + 8 * (r >> 2) + 4 * hf;
                    if (kvl > lq) stt[sti][r] = -3e38f;
                }
        }

        float pm[4] = { -3e38f, -3e38f, -3e38f, -3e38f };
        #pragma unroll
        for (int r = 0; r < 16; r++)
            pm[r & 3] = fmaxf(pm[r & 3], fmaxf(stt[0][r], stt[1][r]));
        float mx = fmaxf(fmaxf(pm[0], pm[1]), fmaxf(pm[2], pm[3]));
        mx = fmaxf(mx, __shfl_xor(mx, 32));

        if (!__all(mx - m_run <= 8.0f)) {
            const float mn = fmaxf(m_run, mx);
            const float alpha = __builtin_amdgcn_exp2f(m_run - mn);
            m_run = mn;
            lsum *= alpha;
            ot[0] *= alpha;
            ot[1] *= alpha;
        }

        float sp[4] = { 0.f, 0.f, 0.f, 0.f };
        #pragma unroll
        for (int sti = 0; sti < 2; sti++)
            #pragma unroll
            for (int r = 0; r < 16; r++) {
                float e = __builtin_amdgcn_exp2f(stt[sti][r] - m_run);
                stt[sti][r] = e;
                sp[r & 3] += e;
            }
        float sum = (sp[0] + sp[1]) + (sp[2] + sp[3]);
        sum += __shfl_xor(sum, 32);
        lsum += sum;

        if (pf) {
            uint2 lo, hi2;
            lo.x  = __builtin_amdgcn_perm(v1, v0, 0x05040100u);
            lo.y  = __builtin_amdgcn_perm(v3, v2, 0x05040100u);
            hi2.x = __builtin_amdgcn_perm(v1, v0, 0x07060302u);
            hi2.y = __builtin_amdgcn_perm(v3, v2, 0x07060302u);
            char* vb = (char*)Vtn;
            *(uint2*)(vb + vd0 * 128 + vp0 * 16 + (ch4 & 1) * 8)       = lo;
            *(uint2*)(vb + (vd0 + 1) * 128 + vp1 * 16 + (ch4 & 1) * 8) = hi2;
        }

        bf16x8 pf4[4];
        #pragma unroll
        for (int ks = 0; ks < 4; ks++) {
            const int sti = ks >> 1, base = 8 * (ks & 1);
            unsigned X0 = pk2bf(stt[sti][base + 0], stt[sti][base + 1]);
            unsigned X1 = pk2bf(stt[sti][base + 2], stt[sti][base + 3]);
            unsigned Y0 = pk2bf(stt[sti][base + 4], stt[sti][base + 5]);
            unsigned Y1 = pk2bf(stt[sti][base + 6], stt[sti][base + 7]);
            asm("v_permlane32_swap_b32 %0, %1" : "+v"(X0), "+v"(Y0));
            asm("v_permlane32_swap_b32 %0, %1" : "+v"(X1), "+v"(Y1));
            unsigned t[4] = { X0, X1, Y0, Y1 };
            pf4[ks] = *(bf16x8*)t;
        }

        __builtin_amdgcn_s_setprio(1);
        #pragma unroll
        for (int dsub = 0; dsub < 2; dsub++) {
            const int dr = dsub * 32 + q;
            #pragma unroll
            for (int ks = 0; ks < 4; ks++) {
                const int phys = (2 * ks + hf) ^ (dr & 7);
                bf16x8 vf = *(const bf16x8*)(Vtc + dr * 64 + phys * 8);
                ot[dsub] = __builtin_amdgcn_mfma_f32_32x32x16_bf16(vf, pf4[ks], ot[dsub], 0, 0, 0);
            }
        }
        __builtin_amdgcn_s_setprio(0);

        __syncthreads();
    }

    unsigned* obuf = (unsigned*)smem;
    const float inv = 1.0f / lsum;
    const int SQ = g * 64 + lq;
    #pragma unroll
    for (int dsub = 0; dsub < 2; dsub++)
        #pragma unroll
        for (int r = 0; r < 16; r += 2) {
            int d = dsub * 32 + (r & 3) + 8 * (r >> 2) + 4 * hf;
            unsigned pk = ((unsigned)(unsigned short)f2bf(ot[dsub][r] * inv)) |
                          (((unsigned)(unsigned short)f2bf(ot[dsub][r + 1] * inv)) << 16);
            obuf[SQ * 34 + (d >> 1)] = pk;
        }
    __syncthreads();
    {
        const int SQ2 = tid >> 1, seg = tid & 1;
        const int g2 = SQ2 >> 6, lq2 = SQ2 & 63;
        const size_t row = (size_t)(bT + qt * 64 + lq2);
        const unsigned* src = obuf + SQ2 * 34 + seg * 16;
        unsigned* dst = (unsigned*)(Y + row * 4096 + g2 * 1024 + h * 64 + seg * 32);
        #pragma unroll
        for (int k = 0; k < 4; k++) {
            uint2 u0 = *(const uint2*)(src + 4 * k);
            uint2 u1 = *(const uint2*)(src + 4 * k + 2);
            uint4 t; t.x = u0.x; t.y = u0.y; t.z = u1.x; t.w = u1.y;
            *(uint4*)(dst + 4 * k) = t;
        }
    }
}

// ---------------------------------------------------------------------------
extern "C" void kernel_launch(void* const* d_in, const int* in_sizes, int n_in,
                              void* d_out, int out_size, void* d_ws, size_t ws_size,
                              hipStream_t stream) {
    const float* x  = (const float*)d_in[0];   // [8192,1024]
    const float* Wa = (const float*)d_in[1];   // [6144,1024]
    const float* Wp = (const float*)d_in[2];   // [1024,4096]
    float* out = (float*)d_out;

    short* qkv = (short*)d_ws;                        // 50331648 shorts
    short* Yb  = qkv + (size_t)8192 * 6144;           // 33554432 shorts
    short* xb  = Yb;                                  // pre-attn reuse of Yb
    short* Wab = Yb + (size_t)8192 * 1024;            // pre-attn reuse of Yb
    short* Wpb = qkv;                                 // post-attn reuse of qkv

    const float QS = 0.18033688011112042f;            // 0.125 * log2(e)
    dim3 blk(256);
    // fused cvt: x -> xb, Wa -> Wab (Q rows scaled)
    cvt_all<<<dim3((8192 + 6144) * 1024 / 8 / 256), blk, 0, stream>>>(x, Wa, xb, QS);
    // qkv = x @ W_attn^T   (M=8192, N=6144, K=1024): 32 x 24 = 768 wgs
    gemm8_bt<<<dim3(768), dim3(512), 0, stream>>>(xb, Wab, qkv, 8192, 6144, 1024, 24);
    // flash attention -> Y   (128 combos x 16 q-tiles, 512 thr)
    attn_fwd<<<dim3(128, 16), dim3(512), 0, stream>>>(qkv, Yb);
    // out = Y @ W_proj^T   (M=8192, N=1024, K=4096): 32 x 8 = 256 wgs
    cvt_bf16<<<dim3(1024 * 4096 / 8 / 256), blk, 0, stream>>>(Wp, Wpb, 1024 * 4096 / 8, 1.0f);
    gemm8_bt2<<<dim3(256), dim3(512), 0, stream>>>(Yb, Wpb, out, 8192, 1024, 4096);
}